// Round 2
// baseline (368.530 us; speedup 1.0000x reference)
//
#include <hip/hip_runtime.h>
#include <hip/hip_bf16.h>

// ---------------------------------------------------------------------------
// MultiHeadAttention fused kernel for MI355X (gfx950)
// B=8 S=4096 Q=32 H=8 D=64 IN=512 NKV=1024
// R6: 80 KiB LDS union (staging aliased with kv/v/P) -> 2 blocks/CU,
//     XCD-aware grid remap (4 hp-blocks sharing an A-tile co-resident on one
//     XCD), k_qproj widened to 16 blocks (64x128 tile, BK=64, swizzled LDS).
// ---------------------------------------------------------------------------

typedef float f32x4 __attribute__((ext_vector_type(4)));
typedef short s16x8 __attribute__((ext_vector_type(8)));

__device__ __forceinline__ unsigned short f2bf(float f) {
  union { __hip_bfloat16 h; unsigned short u; } cv;
  cv.h = __float2bfloat16(f);
  return cv.u;
}
__device__ __forceinline__ float bf2f(unsigned short u) {
  union { unsigned short u; __hip_bfloat16 h; } cv;
  cv.u = u;
  return __bfloat162float(cv.h);
}
__device__ __forceinline__ float tofl(float v) { return v; }
__device__ __forceinline__ float tofl(__hip_bfloat16 v) { return __bfloat162float(v); }

__device__ __forceinline__ f32x4 mfma16(s16x8 a, s16x8 b, f32x4 c) {
  return __builtin_amdgcn_mfma_f32_16x16x32_bf16(a, b, c, 0, 0, 0);
}

// ---------------------------------------------------------------------------
// Inline dtype detection (1 = fp32, 0 = bf16). Reads 64 EVEN u16 entries of
// inputs: bf16 values have plausible exponents (~100%); fp32 arrays put
// mantissa low-halves at even u16 (~12% plausible). Uniform per wave.
// ---------------------------------------------------------------------------
__device__ __forceinline__ int detect_fp32(const unsigned short* __restrict__ in16) {
  unsigned short v = in16[2 * (threadIdx.x & 63)];
  int e = (v >> 7) & 0xFF;
  unsigned long long m = __ballot(e >= 100 && e <= 130);
  return __popcll(m) < 48 ? 1 : 0;
}

// ---------------------------------------------------------------------------
// LDS swizzles.
// Staging tiles [rows][64] bf16 (128 B row): 16B-unit index ^ (row&7).
// kv/v/P tiles [rows][128]: same scheme in 8-elem granules (sw_idx).
// ---------------------------------------------------------------------------
__device__ __forceinline__ unsigned short* stg(unsigned short* buf, int r, int u) {
  return buf + r * 64 + ((u ^ (r & 7)) << 3);
}
__device__ __forceinline__ const unsigned short* stgc(const unsigned short* buf, int r, int u) {
  return buf + r * 64 + ((u ^ (r & 7)) << 3);
}
__device__ __forceinline__ int sw_idx(int r, int c) {
  return r * 128 + ((((c >> 3) ^ (r & 7)) << 3) | (c & 7));
}

// 16-element (along K) register chunk, stored to LDS as bf16
template <typename T> struct RegChunk;
template <> struct RegChunk<float> {
  float4 v[4];
  __device__ __forceinline__ void load(const float* p) {
    const float4* q = reinterpret_cast<const float4*>(p);
    v[0] = q[0]; v[1] = q[1]; v[2] = q[2]; v[3] = q[3];
  }
  __device__ __forceinline__ void store2(unsigned short* d0, unsigned short* d1) {  // swizzled
    union { unsigned short u[16]; s16x8 w[2]; } t;
    const float* f = reinterpret_cast<const float*>(v);
#pragma unroll
    for (int i = 0; i < 16; ++i) t.u[i] = f2bf(f[i]);
    *reinterpret_cast<s16x8*>(d0) = t.w[0];
    *reinterpret_cast<s16x8*>(d1) = t.w[1];
  }
};
template <> struct RegChunk<__hip_bfloat16> {
  s16x8 v[2];
  __device__ __forceinline__ void load(const __hip_bfloat16* p) {
    const s16x8* q = reinterpret_cast<const s16x8*>(p);
    v[0] = q[0]; v[1] = q[1];
  }
  __device__ __forceinline__ void store2(unsigned short* d0, unsigned short* d1) {
    *reinterpret_cast<s16x8*>(d0) = v[0];
    *reinterpret_cast<s16x8*>(d1) = v[1];
  }
};

// ---------------------------------------------------------------------------
// q projection: qws[256][512] = queries[256][512] @ Wq^T + bq
// R6: grid (4 Mtiles of 64, 4 Ntiles of 128), 256 thr (4 waves), BK=64,
// swizzled staging. Wave (wi,wj) owns 32x64; acc[2][4].
// MFMA 16x16x32_bf16 layouts (HW-verified):
//   A: m=lane&15, k=quad*8+j ; B: n=lane&15, k=quad*8+j ;
//   D: col=lane&15, row=quad*4+reg
// ---------------------------------------------------------------------------
template <typename T>
__device__ __forceinline__ void qproj_body(const T* __restrict__ queries,
                                           const T* __restrict__ Wq,
                                           const T* __restrict__ bq,
                                           unsigned short* __restrict__ qws,
                                           unsigned short* Abuf, unsigned short* Bbuf) {
  const int Mt = blockIdx.x, Nt = blockIdx.y;
  const int tid = threadIdx.x;
  const int w = tid >> 6, l = tid & 63;
  const int quad = l >> 4, l16 = l & 15;
  const int wi = (w >> 1) * 32, wj = (w & 1) * 64;

  // staging: A 64x64 (1 chunk/thr), B 128x64 (2 chunks/thr)
  const int sar = tid >> 2, sag = (tid & 3) * 2;       // A row, granule base
  const int sbr = tid >> 1, sbg = (tid & 1) * 4;       // B row, granule base
  const T* Asrc = queries + ((size_t)(Mt * 64 + sar)) * 512 + sag * 8;
  const T* Bsrc = Wq + ((size_t)(Nt * 128 + sbr)) * 512 + sbg * 8;
  unsigned short* ad0 = stg(Abuf, sar, sag);
  unsigned short* ad1 = stg(Abuf, sar, sag + 1);
  unsigned short* bd0 = stg(Bbuf, sbr, sbg);
  unsigned short* bd1 = stg(Bbuf, sbr, sbg + 1);
  unsigned short* bd2 = stg(Bbuf, sbr, sbg + 2);
  unsigned short* bd3 = stg(Bbuf, sbr, sbg + 3);

  const f32x4 zero4 = {0.f, 0.f, 0.f, 0.f};
  f32x4 acc[2][4];
#pragma unroll
  for (int i = 0; i < 2; ++i)
#pragma unroll
    for (int j = 0; j < 4; ++j) acc[i][j] = zero4;

  RegChunk<T> ra, rb0, rb1;
  ra.load(Asrc);
  rb0.load(Bsrc);
  rb1.load(Bsrc + 16);
#pragma unroll
  for (int it = 0; it < 8; ++it) {
    __syncthreads();
    ra.store2(ad0, ad1);
    rb0.store2(bd0, bd1);
    rb1.store2(bd2, bd3);
    if (it < 7) {
      ra.load(Asrc + (it + 1) * 64);
      rb0.load(Bsrc + (it + 1) * 64);
      rb1.load(Bsrc + (it + 1) * 64 + 16);
    }
    __syncthreads();
#pragma unroll
    for (int kk2 = 0; kk2 < 2; ++kk2) {
      s16x8 af[2], bfr[4];
#pragma unroll
      for (int i = 0; i < 2; ++i)
        af[i] = *reinterpret_cast<const s16x8*>(stgc(Abuf, wi + i * 16 + l16, kk2 * 4 + quad));
#pragma unroll
      for (int j = 0; j < 4; ++j)
        bfr[j] = *reinterpret_cast<const s16x8*>(stgc(Bbuf, wj + j * 16 + l16, kk2 * 4 + quad));
#pragma unroll
      for (int i = 0; i < 2; ++i)
#pragma unroll
        for (int j = 0; j < 4; ++j) acc[i][j] = mfma16(af[i], bfr[j], acc[i][j]);
    }
  }

#pragma unroll
  for (int j = 0; j < 4; ++j) {
    float bb = tofl(bq[Nt * 128 + wj + j * 16 + l16]);
#pragma unroll
    for (int i = 0; i < 2; ++i)
#pragma unroll
      for (int rg = 0; rg < 4; ++rg) {
        int row = Mt * 64 + wi + i * 16 + quad * 4 + rg;
        int col = Nt * 128 + wj + j * 16 + l16;
        qws[(size_t)row * 512 + col] = f2bf(acc[i][j][rg] + bb);
      }
  }
}

__global__ __launch_bounds__(256) void k_qproj(const void* queries, const void* Wq,
                                               const void* bq, unsigned short* qws,
                                               const unsigned short* __restrict__ det) {
  __shared__ unsigned short Abuf[64 * 64];    //  8 KiB
  __shared__ unsigned short Bbuf[128 * 64];   // 16 KiB
  if (detect_fp32(det))
    qproj_body<float>((const float*)queries, (const float*)Wq, (const float*)bq, qws, Abuf,
                      Bbuf);
  else
    qproj_body<__hip_bfloat16>((const __hip_bfloat16*)queries, (const __hip_bfloat16*)Wq,
                               (const __hip_bfloat16*)bq, qws, Abuf, Bbuf);
}

// ---------------------------------------------------------------------------
// Fused kernel. Flat grid 1024 blocks, 512 threads; XCD-aware remap:
//   x = 32*(g/8) + 8*hp + (g%8), g = stile + 32*b
// so the 4 hp-blocks sharing an A-tile sit on ONE XCD in the same round.
// ONE BK=64 K-loop computes K-block (128x128) and V-block (128x128): waves
// 0-3 own K quadrants, 4-7 own V. LDS: staging (48K) aliased under
// kv/v/P (80K) -> 80 KiB total -> 2 blocks/CU.
// ---------------------------------------------------------------------------
template <typename T>
__device__ __forceinline__ void fused_body(
    const T* __restrict__ inputs, const T* __restrict__ masks,
    const T* __restrict__ Wkv, const T* __restrict__ bkv,
    const unsigned short* __restrict__ qws,
    float* __restrict__ num, float* __restrict__ den,
    unsigned short* Abuf, unsigned short* Bbuf,
    unsigned short* kvbuf, unsigned short* vbuf, unsigned short* Pbuf) {
  const int x = blockIdx.x;            // 0..1023
  const int hp = (x >> 3) & 3;         // 0..3
  const int g = (x & 7) + (x >> 5) * 8;  // 0..255
  const int stile = g & 31;            // 0..31
  const int b = g >> 5;                // 0..7
  const int s0 = stile * 128;
  const int tid = threadIdx.x;
  const int w = tid >> 6;        // 0..7
  const int l = tid & 63;
  const int quad = l >> 4;
  const int l16 = l & 15;
  const int which = w >> 2;           // 0 = K-output waves, 1 = V
  const int wr = ((w >> 1) & 1) * 64;
  const int wc = (w & 1) * 64;

  const f32x4 zero4 = {0.f, 0.f, 0.f, 0.f};
  f32x4 acc[4][4];
#pragma unroll
  for (int i = 0; i < 4; ++i)
#pragma unroll
    for (int j = 0; j < 4; ++j) acc[i][j] = zero4;

  // staging mapping: thread -> (row sr, chunk-col sc) ; 1 A + 2 B chunks
  const int sr = tid >> 2;  // 0..127
  const int sc = tid & 3;   // 16-elem chunk within 64-wide K-slice
  const T* Asrc = inputs + ((size_t)(b * 4096 + s0 + sr)) * 512 + sc * 16;
  const T* BKs = Wkv + ((size_t)(hp * 128 + sr)) * 512 + sc * 16;
  const T* BVs = Wkv + ((size_t)(512 + hp * 128 + sr)) * 512 + sc * 16;
  unsigned short* ad0 = stg(Abuf, sr, sc * 2);
  unsigned short* ad1 = stg(Abuf, sr, sc * 2 + 1);
  unsigned short* bk0 = stg(Bbuf, sr, sc * 2);
  unsigned short* bk1 = stg(Bbuf, sr, sc * 2 + 1);
  unsigned short* bv0 = stg(Bbuf, 128 + sr, sc * 2);
  unsigned short* bv1 = stg(Bbuf, 128 + sr, sc * 2 + 1);

  // 2-deep A prefetch (HBM-streamed), 1-deep B prefetch (Wkv is L2-hot).
  RegChunk<T> ra0, ra1, rbk, rbv;
  ra0.load(Asrc);
  ra1.load(Asrc + 64);
  rbk.load(BKs);
  rbv.load(BVs);

#pragma unroll
  for (int it2 = 0; it2 < 4; ++it2) {
#pragma unroll
    for (int ph = 0; ph < 2; ++ph) {
      const int it = it2 * 2 + ph;
      RegChunk<T>& ra = ph ? ra1 : ra0;
      __syncthreads();  // staging buffers free
      ra.store2(ad0, ad1);
      rbk.store2(bk0, bk1);
      rbv.store2(bv0, bv1);
      if (it < 6) ra.load(Asrc + (it + 2) * 64);
      if (it < 7) {
        rbk.load(BKs + (it + 1) * 64);
        rbv.load(BVs + (it + 1) * 64);
      }
      __syncthreads();  // staging visible
#pragma unroll
      for (int kk2 = 0; kk2 < 2; ++kk2) {
        s16x8 af[4], bfr[4];
#pragma unroll
        for (int i = 0; i < 4; ++i)
          af[i] = *reinterpret_cast<const s16x8*>(
              stgc(Abuf, wr + i * 16 + l16, kk2 * 4 + quad));
#pragma unroll
        for (int j = 0; j < 4; ++j)
          bfr[j] = *reinterpret_cast<const s16x8*>(
              stgc(Bbuf, which * 128 + wc + j * 16 + l16, kk2 * 4 + quad));
#pragma unroll
        for (int i = 0; i < 4; ++i)
#pragma unroll
          for (int j = 0; j < 4; ++j) acc[i][j] = mfma16(af[i], bfr[j], acc[i][j]);
      }
    }
  }
  __syncthreads();  // staging dead; kv/v/P alias the same LDS from here on

  // spill acc(+bias) to kvbuf (K, [s][c]) / vbuf (V, [c][s] transposed)
#pragma unroll
  for (int j = 0; j < 4; ++j) {
    float bb = tofl(bkv[which * 512 + hp * 128 + wc + j * 16 + l16]);
#pragma unroll
    for (int i = 0; i < 4; ++i)
#pragma unroll
      for (int rg = 0; rg < 4; ++rg) {
        int sl = wr + i * 16 + quad * 4 + rg;  // s-row (local)
        int c = wc + j * 16 + l16;             // kv col (local, = d)
        unsigned short bv = f2bf(acc[i][j][rg] + bb);
        if (which == 0)
          kvbuf[sw_idx(sl, c)] = bv;
        else
          vbuf[sw_idx(c, sl)] = bv;
      }
  }
  __syncthreads();

  // ---- u-GEMM: u[2h][32q][128s]; wave -> (hh, mt, s-half) ----
  const int hh = w >> 2, mt = (w >> 1) & 1, sh = w & 1;
  {
    f32x4 ua[4];
#pragma unroll
    for (int j = 0; j < 4; ++j) ua[j] = zero4;
#pragma unroll
    for (int kk = 0; kk < 2; ++kk) {
      s16x8 aq = *reinterpret_cast<const s16x8*>(
          qws + ((size_t)(b * 32 + mt * 16 + l16)) * 512 + hp * 128 + hh * 64 + kk * 32 +
          quad * 8);
#pragma unroll
      for (int j = 0; j < 4; ++j) {
        s16x8 bk = *reinterpret_cast<const s16x8*>(
            &kvbuf[sw_idx(sh * 64 + j * 16 + l16, hh * 64 + kk * 32 + quad * 8)]);
        ua[j] = mfma16(aq, bk, ua[j]);
      }
    }
    const float scale = 0.044194173824159216f;  // 1/sqrt(512)
    float dsum[4] = {0.f, 0.f, 0.f, 0.f};
#pragma unroll
    for (int j = 0; j < 4; ++j) {
      int scol = sh * 64 + j * 16 + l16;
      float mask = tofl(masks[(size_t)b * 4096 + s0 + scol]);
#pragma unroll
      for (int rg = 0; rg < 4; ++rg) {
        int qrow = mt * 16 + quad * 4 + rg;
        float uv = ua[j][rg] * scale;
        // elu: for uv<=0, expf(uv)-1 in (-1,0] -> lower clip at -15 is dead
        float e = uv > 0.f ? uv : (__expf(uv) - 1.f);
        e = fminf(e, 15.f);
        float p = __expf(e) * mask;
        unsigned short pu = f2bf(p);
        Pbuf[sw_idx(hh * 32 + qrow, scol)] = pu;
        dsum[rg] += bf2f(pu);  // sum the ROUNDED value num-GEMM will use
      }
    }
    // den: shuffle-reduce the 16 lanes of each quad; both s-halves atomicAdd
#pragma unroll
    for (int rg = 0; rg < 4; ++rg) {
      float s = dsum[rg];
      s += __shfl_xor(s, 1);
      s += __shfl_xor(s, 2);
      s += __shfl_xor(s, 4);
      s += __shfl_xor(s, 8);
      if (l16 == 0) {
        int qrow = mt * 16 + quad * 4 + rg;
        atomicAdd(&den[((size_t)(b * 32 + qrow)) * 8 + hp * 2 + hh], s);
      }
    }
  }
  __syncthreads();  // Pbuf complete

  // ---- num-GEMM: num[2h][32q][64d]; wave -> (hh, mt, d-half) ----
  {
    const int dh = w & 1;
    f32x4 na[2];
    na[0] = zero4;
    na[1] = zero4;
#pragma unroll
    for (int kk = 0; kk < 4; ++kk) {
      s16x8 ap = *reinterpret_cast<const s16x8*>(
          &Pbuf[sw_idx(hh * 32 + mt * 16 + l16, kk * 32 + quad * 8)]);
#pragma unroll
      for (int jj = 0; jj < 2; ++jj) {
        int j = dh * 2 + jj;
        s16x8 bv = *reinterpret_cast<const s16x8*>(
            &vbuf[sw_idx(hh * 64 + j * 16 + l16, kk * 32 + quad * 8)]);
        na[jj] = mfma16(ap, bv, na[jj]);
      }
    }
    const int h = hp * 2 + hh;
#pragma unroll
    for (int jj = 0; jj < 2; ++jj) {
      int d = (dh * 2 + jj) * 16 + l16;
#pragma unroll
      for (int rg = 0; rg < 4; ++rg) {
        int qrow = mt * 16 + quad * 4 + rg;
        atomicAdd(&num[(((size_t)(b * 32 + qrow)) * 8 + h) * 64 + d], na[jj][rg]);
      }
    }
  }
}

__global__ __launch_bounds__(512, 4) void k_fused(const void* inputs, const void* masks,
                                                  const void* Wkv, const void* bkv,
                                                  const unsigned short* __restrict__ qws,
                                                  float* __restrict__ num,
                                                  float* __restrict__ den) {
  // 80 KiB arena: K-loop uses [Abuf 16K | Bbuf 32K]; afterwards the same
  // bytes hold [kvbuf 32K | vbuf 32K | Pbuf 16K]. 2 blocks/CU.
  __shared__ unsigned short smem[40960];
  unsigned short* Abuf = smem;            // 128*64
  unsigned short* Bbuf = smem + 8192;     // 256*64
  unsigned short* kvbuf = smem;           // 128*128
  unsigned short* vbuf = smem + 16384;    // 128*128
  unsigned short* Pbuf = smem + 32768;    // 64*128
  if (detect_fp32((const unsigned short*)inputs))
    fused_body<float>((const float*)inputs, (const float*)masks, (const float*)Wkv,
                      (const float*)bkv, qws, num, den, Abuf, Bbuf, kvbuf, vbuf, Pbuf);
  else
    fused_body<__hip_bfloat16>((const __hip_bfloat16*)inputs, (const __hip_bfloat16*)masks,
                               (const __hip_bfloat16*)Wkv, (const __hip_bfloat16*)bkv, qws,
                               num, den, Abuf, Bbuf, kvbuf, vbuf, Pbuf);
}

// ---------------------------------------------------------------------------
__global__ __launch_bounds__(256) void k_div(const float* __restrict__ num,
                                             const float* __restrict__ den, void* out,
                                             const unsigned short* __restrict__ det) {
  int i = blockIdx.x * 256 + threadIdx.x;
  float v = num[i] / den[i >> 6];
  if (detect_fp32(det))
    ((float*)out)[i] = v;
  else
    ((__hip_bfloat16*)out)[i] = __float2bfloat16(v);
}

// ---------------------------------------------------------------------------
extern "C" void kernel_launch(void* const* d_in, const int* in_sizes, int n_in,
                              void* d_out, int out_size, void* d_ws, size_t ws_size,
                              hipStream_t stream) {
  // d_in: 0 inputs, 1 queries, 2 masks, 3 Wkv, 4 bkv, 5 Wq, 6 bq
  // ws: [1024] den 2048 f32 ; [16384] num 131072 f32 ;
  //     [540672] qws 131072 u16 -> 802816 bytes
  if (ws_size < 802816) return;
  char* ws = (char*)d_ws;
  float* den = (float*)(ws + 1024);
  float* num = (float*)(ws + 16384);
  unsigned short* qws = (unsigned short*)(ws + 540672);

  hipMemsetAsync(d_ws, 0, 540672, stream);

  dim3 gq(4, 4);
  k_qproj<<<gq, 256, 0, stream>>>(d_in[1], d_in[5], d_in[6], qws,
                                  (const unsigned short*)d_in[0]);

  k_fused<<<1024, 512, 0, stream>>>(d_in[0], d_in[2], d_in[3], d_in[4], qws, num, den);

  k_div<<<512, 256, 0, stream>>>(num, den, d_out, (const unsigned short*)d_in[0]);
}

// Round 4
// 310.468 us; speedup vs baseline: 1.1870x; 1.1870x over previous
//
#include <hip/hip_runtime.h>
#include <hip/hip_bf16.h>
#include <hip/hip_cooperative_groups.h>

// ---------------------------------------------------------------------------
// MultiHeadAttention fully-fused cooperative kernel for MI355X (gfx950)
// B=8 S=4096 Q=32 H=8 D=64 IN=512 NKV=1024
// R8: R7 with num-GEMM vbuf head-offset fix (vbuf row = hh*64 + dh*32 + ...).
//     ONE cooperative dispatch (zero+qproj | KV+attention | divide).
//     256 blocks x 512 thr, 1 block/CU (LDS 136K). Each block: batch b,
//     two 64-row s-tiles, ALL 4 head-pairs over one LDS-resident bf16 A-tile
//     (A fetched from HBM exactly once). Continuous dbuf Wkv chunk stream,
//     1 barrier/K-step. acc[2][4]=32 VGPRs -> no spills.
// ---------------------------------------------------------------------------

typedef float f32x4 __attribute__((ext_vector_type(4)));
typedef short s16x8 __attribute__((ext_vector_type(8)));

__device__ __forceinline__ unsigned short f2bf(float f) {
  union { __hip_bfloat16 h; unsigned short u; } cv;
  cv.h = __float2bfloat16(f);
  return cv.u;
}
__device__ __forceinline__ float bf2f(unsigned short u) {
  union { unsigned short u; __hip_bfloat16 h; } cv;
  cv.u = u;
  return __bfloat162float(cv.h);
}
__device__ __forceinline__ float tofl(float v) { return v; }
__device__ __forceinline__ float tofl(__hip_bfloat16 v) { return __bfloat162float(v); }

__device__ __forceinline__ f32x4 mfma16(s16x8 a, s16x8 b, f32x4 c) {
  return __builtin_amdgcn_mfma_f32_16x16x32_bf16(a, b, c, 0, 0, 0);
}

// dtype detection (1 = fp32, 0 = bf16): even u16 entries of a bf16 array are
// real bf16 (plausible exponent ~100%); of an fp32 array are mantissa halves.
__device__ __forceinline__ int detect_fp32(const unsigned short* __restrict__ in16) {
  unsigned short v = in16[2 * (threadIdx.x & 63)];
  int e = (v >> 7) & 0xFF;
  unsigned long long m = __ballot(e >= 100 && e <= 130);
  return __popcll(m) < 48 ? 1 : 0;
}

// ---------------------------------------------------------------------------
// LDS address helpers (all swizzled so 16-lane stride-row fragment reads hit
// 8 distinct 16B slots = 2 lanes/bank-group = conflict-free).
// Abig [64][512] bf16: XOR granule (8 elems) with row within 8-granule group.
__device__ __forceinline__ int abig_addr(int r, int g) {
  return r * 512 + (((g & ~7) | ((g ^ r) & 7)) << 3);
}
// Bstg [256][32] bf16: 4 granules/row, XOR with (row>>1).
__device__ __forceinline__ int bstg_addr(int r, int g) {
  return r * 32 + (((g ^ (r >> 1)) & 3) << 3);
}
// 128-col tiles (kvbuf [64][128]):
__device__ __forceinline__ int sw_idx(int r, int c) {
  return r * 128 + ((((c >> 3) ^ (r & 7)) << 3) | (c & 7));
}
// 64-col tiles (vbuf [128][64], Pbuf [64][64]):
__device__ __forceinline__ int sw64(int r, int c) {
  return r * 64 + ((((c >> 3) ^ (r & 7)) << 3) | (c & 7));
}

// 8-element bf16 fragment load from global (with fp32->bf16 convert)
template <typename T>
__device__ __forceinline__ s16x8 load_frag8(const T* p);
template <>
__device__ __forceinline__ s16x8 load_frag8<float>(const float* p) {
  const float4* q = reinterpret_cast<const float4*>(p);
  float4 a = q[0], b = q[1];
  union { unsigned short u[8]; s16x8 w; } t;
  t.u[0] = f2bf(a.x); t.u[1] = f2bf(a.y); t.u[2] = f2bf(a.z); t.u[3] = f2bf(a.w);
  t.u[4] = f2bf(b.x); t.u[5] = f2bf(b.y); t.u[6] = f2bf(b.z); t.u[7] = f2bf(b.w);
  return t.w;
}
template <>
__device__ __forceinline__ s16x8 load_frag8<__hip_bfloat16>(const __hip_bfloat16* p) {
  return *reinterpret_cast<const s16x8*>(p);
}

// 16-element register chunk (B staging), stored to two swizzled 16B slots
template <typename T> struct RegChunk;
template <> struct RegChunk<float> {
  float4 v[4];
  __device__ __forceinline__ void load(const float* p) {
    const float4* q = reinterpret_cast<const float4*>(p);
    v[0] = q[0]; v[1] = q[1]; v[2] = q[2]; v[3] = q[3];
  }
  __device__ __forceinline__ void store2(unsigned short* d0, unsigned short* d1) {
    union { unsigned short u[16]; s16x8 w[2]; } t;
    const float* f = reinterpret_cast<const float*>(v);
#pragma unroll
    for (int i = 0; i < 16; ++i) t.u[i] = f2bf(f[i]);
    *reinterpret_cast<s16x8*>(d0) = t.w[0];
    *reinterpret_cast<s16x8*>(d1) = t.w[1];
  }
};
template <> struct RegChunk<__hip_bfloat16> {
  s16x8 v[2];
  __device__ __forceinline__ void load(const __hip_bfloat16* p) {
    const s16x8* q = reinterpret_cast<const s16x8*>(p);
    v[0] = q[0]; v[1] = q[1];
  }
  __device__ __forceinline__ void store2(unsigned short* d0, unsigned short* d1) {
    *reinterpret_cast<s16x8*>(d0) = v[0];
    *reinterpret_cast<s16x8*>(d1) = v[1];
  }
};

// ---------------------------------------------------------------------------
template <typename T>
__device__ __forceinline__ void body(
    const T* __restrict__ inputs, const T* __restrict__ queries,
    const T* __restrict__ masks, const T* __restrict__ Wkv,
    const T* __restrict__ bkv, const T* __restrict__ Wq, const T* __restrict__ bq,
    char* __restrict__ ws, void* __restrict__ out, unsigned short* smem) {
  const int tid = threadIdx.x, bid = blockIdx.x;
  const int w = tid >> 6, l = tid & 63;
  const int quad = l >> 4, l16 = l & 15;
  const f32x4 zero4 = {0.f, 0.f, 0.f, 0.f};

  float* den = (float*)ws;                                  // 2048 f32
  float* num = (float*)(ws + 8192);                         // 131072 f32
  unsigned short* qws = (unsigned short*)(ws + 532480);     // 256x512 bf16

  unsigned short* Abig = smem;            // [64][512]  64 KiB
  unsigned short* Bstg = smem + 32768;    // 2x[256][32] 32 KiB
  unsigned short* kvbuf = smem + 49152;   // [64][128]  16 KiB
  unsigned short* vbuf = smem + 57344;    // [128][64]  16 KiB
  unsigned short* Pbuf = smem + 65536;    // [64][64]    8 KiB

  // ================= phase 0: zero num/den + q projection =================
  {
    float* zp = (float*)ws;  // 133120 f32 contiguous (den then num)
    zp[bid * 520 + tid] = 0.f;
    if (tid < 8) zp[bid * 520 + 512 + tid] = 0.f;
  }
  if (bid < 64) {
    // qws[256][512] = queries @ Wq^T + bq ; 8x8 grid of 32x64 tiles,
    // fragments read straight from L2 (K=512 unrolled).
    const int Mt = bid >> 3, Nt = bid & 7;
    const int mi = w >> 2, nj = w & 3;
    const size_t qroff = (size_t)(Mt * 32 + mi * 16 + l16) * 512 + quad * 8;
    const size_t wroff = (size_t)(Nt * 64 + nj * 16 + l16) * 512 + quad * 8;
    f32x4 qa = zero4;
#pragma unroll
    for (int k0 = 0; k0 < 512; k0 += 32) {
      s16x8 aq = load_frag8(queries + qroff + k0);
      s16x8 bw = load_frag8(Wq + wroff + k0);
      qa = mfma16(aq, bw, qa);
    }
    float bb = tofl(bq[Nt * 64 + nj * 16 + l16]);
#pragma unroll
    for (int rg = 0; rg < 4; ++rg)
      qws[(size_t)(Mt * 32 + mi * 16 + quad * 4 + rg) * 512 + Nt * 64 + nj * 16 + l16] =
          f2bf(qa[rg] + bb);
  }
  cooperative_groups::this_grid().sync();

  // ================= phase 1: KV projection + attention ===================
  const int b = bid >> 5;          // batch
  const int st2 = bid & 31;        // s-tile pair -> tiles st2*2, st2*2+1
  // K-loop wave mapping: which (K or V), s-half wr, d-half wc
  const int which = w >> 2;
  const int wr = ((w >> 1) & 1) * 32;
  const int wc = (w & 1) * 64;
  // attention wave mapping
  const int hh = w >> 2, mt = (w >> 1) & 1, sh = w & 1, dh = w & 1;

  // B staging constants: thread -> (Wkv local row sr, granule pair sgb)
  const int sr = tid >> 1;
  const int sgb = (tid & 1) * 2;
  const int rbase = (sr < 128) ? sr : (384 + sr);  // +hp*128 = global Wkv row
  const int koff = sgb * 8;
  unsigned short* wA0 = &Bstg[bstg_addr(sr, sgb)];
  unsigned short* wA1 = &Bstg[bstg_addr(sr, sgb + 1)];
  unsigned short* wB0 = wA0 + 8192;
  unsigned short* wB1 = wA1 + 8192;
  // B fragment read offsets (within one 8192-elem buffer)
  int ro[4];
#pragma unroll
  for (int j = 0; j < 4; ++j)
    ro[j] = bstg_addr(which * 128 + wc + j * 16 + l16, quad);

  RegChunk<T> rb0, rb1;
  auto bload = [&](RegChunk<T>& r, int m) {
    if (m < 128) {
      int hp_ = (m >> 4) & 3;
      int it_ = m & 15;
      r.load(Wkv + ((size_t)(hp_ * 128 + rbase)) * 512 + it_ * 32 + koff);
    }
  };
  auto stageA = [&](int stg) {  // stage s-tile stg (64 rows) into Abig
    const int s0_ = stg * 64;
    const int ar = tid >> 3, agb = (tid & 7) * 8;
    const T* src = inputs + ((size_t)(b * 4096 + s0_ + ar)) * 512;
#pragma unroll
    for (int j = 0; j < 8; ++j) {
      int g = agb + j;
      s16x8 vch = load_frag8(src + g * 8);
      *reinterpret_cast<s16x8*>(&Abig[abig_addr(ar, g)]) = vch;
    }
  };

  f32x4 acc[2][4];
  int n = 0;  // consumed Wkv chunk counter (8 segments x 16 chunks = 128)

  auto kiter = [&](int cp, RegChunk<T>& rb, unsigned short* d0, unsigned short* d1) {
    // stage chunk n+1 into parity cp^1, refill rb with chunk n+3
    if (n + 1 < 128) {
      rb.store2(d0, d1);
      bload(rb, n + 3);
    }
    const int gb = (n & 15) * 4;
    s16x8 af0, af1, bf0, bf1, bf2, bf3;
    {
      int r0 = wr + l16, g = gb + quad;
      af0 = *reinterpret_cast<const s16x8*>(&Abig[abig_addr(r0, g)]);
      int r1 = wr + 16 + l16;
      af1 = *reinterpret_cast<const s16x8*>(&Abig[abig_addr(r1, g)]);
    }
    const unsigned short* bb = Bstg + cp * 8192;
    bf0 = *reinterpret_cast<const s16x8*>(&bb[ro[0]]);
    bf1 = *reinterpret_cast<const s16x8*>(&bb[ro[1]]);
    bf2 = *reinterpret_cast<const s16x8*>(&bb[ro[2]]);
    bf3 = *reinterpret_cast<const s16x8*>(&bb[ro[3]]);
    acc[0][0] = mfma16(af0, bf0, acc[0][0]);
    acc[0][1] = mfma16(af0, bf1, acc[0][1]);
    acc[0][2] = mfma16(af0, bf2, acc[0][2]);
    acc[0][3] = mfma16(af0, bf3, acc[0][3]);
    acc[1][0] = mfma16(af1, bf0, acc[1][0]);
    acc[1][1] = mfma16(af1, bf1, acc[1][1]);
    acc[1][2] = mfma16(af1, bf2, acc[1][2]);
    acc[1][3] = mfma16(af1, bf3, acc[1][3]);
    __syncthreads();
    ++n;
  };

  // prologue: chunks 0,1 in regs; A-tile 0; stage chunk 0 -> buf0
  bload(rb0, 0);
  bload(rb1, 1);
  stageA(st2 * 2);
  rb0.store2(wA0, wA1);
  bload(rb0, 2);
  __syncthreads();

  const float scale = 0.044194173824159216f;  // 1/sqrt(512)

  for (int st = 0; st < 2; ++st) {
    const int s0 = (st2 * 2 + st) * 64;
    for (int hpi = 0; hpi < 4; ++hpi) {
#pragma unroll
      for (int i = 0; i < 2; ++i)
#pragma unroll
        for (int j = 0; j < 4; ++j) acc[i][j] = zero4;

      // ---- K-loop: 16 chunks, 1 barrier each ----
      for (int it2 = 0; it2 < 8; ++it2) {
        kiter(0, rb1, wB0, wB1);  // n even: consume buf0, stage buf1
        kiter(1, rb0, wA0, wA1);  // n odd : consume buf1, stage buf0
      }

      // ---- spill acc(+bias): K -> kvbuf [s][c], V -> vbuf [c][s] ----
#pragma unroll
      for (int j = 0; j < 4; ++j) {
        float bb = tofl(bkv[which * 512 + hpi * 128 + wc + j * 16 + l16]);
#pragma unroll
        for (int i = 0; i < 2; ++i)
#pragma unroll
          for (int rg = 0; rg < 4; ++rg) {
            int sl = wr + i * 16 + quad * 4 + rg;
            int c = wc + j * 16 + l16;
            unsigned short bv = f2bf(acc[i][j][rg] + bb);
            if (which == 0) kvbuf[sw_idx(sl, c)] = bv;
            else vbuf[sw64(c, sl)] = bv;
          }
      }
      __syncthreads();

      // ---- u-GEMM + P + den: wave -> (hh, mt, sh) ----
      {
        f32x4 ua0 = zero4, ua1 = zero4;
#pragma unroll
        for (int kk = 0; kk < 2; ++kk) {
          s16x8 aq = *reinterpret_cast<const s16x8*>(
              &qws[((size_t)(b * 32 + mt * 16 + l16)) * 512 + hpi * 128 + hh * 64 +
                   kk * 32 + quad * 8]);
          s16x8 bk0 = *reinterpret_cast<const s16x8*>(
              &kvbuf[sw_idx(sh * 32 + l16, hh * 64 + kk * 32 + quad * 8)]);
          s16x8 bk1 = *reinterpret_cast<const s16x8*>(
              &kvbuf[sw_idx(sh * 32 + 16 + l16, hh * 64 + kk * 32 + quad * 8)]);
          ua0 = mfma16(aq, bk0, ua0);
          ua1 = mfma16(aq, bk1, ua1);
        }
        float dsum[4] = {0.f, 0.f, 0.f, 0.f};
#pragma unroll
        for (int j = 0; j < 2; ++j) {
          int scol = sh * 32 + j * 16 + l16;
          float mask = tofl(masks[(size_t)b * 4096 + s0 + scol]);
          const f32x4& ua = (j == 0) ? ua0 : ua1;
#pragma unroll
          for (int rg = 0; rg < 4; ++rg) {
            float uv = ua[rg] * scale;
            float e = uv > 0.f ? uv : (__expf(uv) - 1.f);  // elu (low clip dead)
            e = fminf(e, 15.f);
            float p = __expf(e) * mask;
            unsigned short pu = f2bf(p);
            Pbuf[sw64(hh * 32 + mt * 16 + quad * 4 + rg, scol)] = pu;
            dsum[rg] += bf2f(pu);  // sum the ROUNDED value num-GEMM uses
          }
        }
#pragma unroll
        for (int rg = 0; rg < 4; ++rg) {
          float s = dsum[rg];
          s += __shfl_xor(s, 1);
          s += __shfl_xor(s, 2);
          s += __shfl_xor(s, 4);
          s += __shfl_xor(s, 8);
          if (l16 == 0) {
            int qrow = mt * 16 + quad * 4 + rg;
            atomicAdd(&den[((size_t)(b * 32 + qrow)) * 8 + hpi * 2 + hh], s);
          }
        }
      }
      __syncthreads();

      // ---- num-GEMM: wave -> (hh, mt, dh) ----
      {
        f32x4 na0 = zero4, na1 = zero4;
#pragma unroll
        for (int kk = 0; kk < 2; ++kk) {
          s16x8 ap = *reinterpret_cast<const s16x8*>(
              &Pbuf[sw64(hh * 32 + mt * 16 + l16, kk * 32 + quad * 8)]);
          s16x8 bv0 = *reinterpret_cast<const s16x8*>(
              &vbuf[sw64(hh * 64 + dh * 32 + l16, kk * 32 + quad * 8)]);
          s16x8 bv1 = *reinterpret_cast<const s16x8*>(
              &vbuf[sw64(hh * 64 + dh * 32 + 16 + l16, kk * 32 + quad * 8)]);
          na0 = mfma16(ap, bv0, na0);
          na1 = mfma16(ap, bv1, na1);
        }
#pragma unroll
        for (int rg = 0; rg < 4; ++rg) {
          int qrow = mt * 16 + quad * 4 + rg;
          size_t base = (((size_t)(b * 32 + qrow)) * 8 + hpi * 2 + hh) * 64;
          atomicAdd(&num[base + dh * 32 + l16], na0[rg]);
          atomicAdd(&num[base + dh * 32 + 16 + l16], na1[rg]);
        }
      }
      __syncthreads();
    }
    if (st == 0) {
      stageA(st2 * 2 + 1);
      __syncthreads();
    }
  }

  // ================= phase 2: divide + store ==============================
  cooperative_groups::this_grid().sync();
  {
    int i = bid * 512 + tid;
    float v = num[i] / den[i >> 6];
    if constexpr (sizeof(T) == 4) ((float*)out)[i] = v;
    else ((__hip_bfloat16*)out)[i] = __float2bfloat16(v);
  }
}

__global__ __launch_bounds__(512, 2) void k_all(const void* inputs, const void* queries,
                                                const void* masks, const void* Wkv,
                                                const void* bkv, const void* Wq,
                                                const void* bq, void* ws, void* out) {
  __shared__ unsigned short smem[69632];  // 136 KiB arena
  if (detect_fp32((const unsigned short*)inputs))
    body<float>((const float*)inputs, (const float*)queries, (const float*)masks,
                (const float*)Wkv, (const float*)bkv, (const float*)Wq, (const float*)bq,
                (char*)ws, out, smem);
  else
    body<__hip_bfloat16>((const __hip_bfloat16*)inputs, (const __hip_bfloat16*)queries,
                         (const __hip_bfloat16*)masks, (const __hip_bfloat16*)Wkv,
                         (const __hip_bfloat16*)bkv, (const __hip_bfloat16*)Wq,
                         (const __hip_bfloat16*)bq, (char*)ws, out, smem);
}

// ---------------------------------------------------------------------------
extern "C" void kernel_launch(void* const* d_in, const int* in_sizes, int n_in,
                              void* d_out, int out_size, void* d_ws, size_t ws_size,
                              hipStream_t stream) {
  // d_in: 0 inputs, 1 queries, 2 masks, 3 Wkv, 4 bkv, 5 Wq, 6 bq
  // ws: [0] den 2048 f32 ; [8192] num 131072 f32 ; [532480] qws 131072 u16
  if (ws_size < 794624) return;
  void* a0 = d_in[0];
  void* a1 = d_in[1];
  void* a2 = d_in[2];
  void* a3 = d_in[3];
  void* a4 = d_in[4];
  void* a5 = d_in[5];
  void* a6 = d_in[6];
  void* a7 = d_ws;
  void* a8 = d_out;
  void* args[9] = {&a0, &a1, &a2, &a3, &a4, &a5, &a6, &a7, &a8};
  hipLaunchCooperativeKernel((void*)k_all, dim3(256), dim3(512), args, 0, stream);
}

// Round 5
// 276.279 us; speedup vs baseline: 1.3339x; 1.1237x over previous
//
#include <hip/hip_runtime.h>
#include <hip/hip_bf16.h>

// ---------------------------------------------------------------------------
// MultiHeadAttention for MI355X (gfx950)
// B=8 S=4096 Q=32 H=8 D=64 IN=512 NKV=1024
// R9: DECOUPLED pipeline (3 regular dispatches, graph-friendly):
//   k_gemm : kv[32768][1024] = inputs@Wkv^T + bkv (bf16, ws) and
//            qws[256][512] = queries@Wq^T + bq, as 2056 x 128x128-tile
//            GEMM blocks (256 thr, 3-4 blocks/CU -> TLP hides staging).
//   k_attn : 256 blocks (stile,b), R1-verified attention math, per-block
//            PARTIALS to ws (no atomics).
//   k_final: reduce 32 partials + divide -> out.
// Fallback: if ws_size < 84.4 MB, R1-verified 3-kernel path.
// ---------------------------------------------------------------------------

typedef float f32x4 __attribute__((ext_vector_type(4)));
typedef short s16x8 __attribute__((ext_vector_type(8)));

__device__ __forceinline__ unsigned short f2bf(float f) {
  union { __hip_bfloat16 h; unsigned short u; } cv;
  cv.h = __float2bfloat16(f);
  return cv.u;
}
__device__ __forceinline__ float bf2f(unsigned short u) {
  union { unsigned short u; __hip_bfloat16 h; } cv;
  cv.u = u;
  return __bfloat162float(cv.h);
}
__device__ __forceinline__ float tofl(float v) { return v; }
__device__ __forceinline__ float tofl(__hip_bfloat16 v) { return __bfloat162float(v); }

__device__ __forceinline__ f32x4 mfma16(s16x8 a, s16x8 b, f32x4 c) {
  return __builtin_amdgcn_mfma_f32_16x16x32_bf16(a, b, c, 0, 0, 0);
}

// dtype detection (1 = fp32, 0 = bf16)
__device__ __forceinline__ int detect_fp32(const unsigned short* __restrict__ in16) {
  unsigned short v = in16[2 * (threadIdx.x & 63)];
  int e = (v >> 7) & 0xFF;
  unsigned long long m = __ballot(e >= 100 && e <= 130);
  return __popcll(m) < 48 ? 1 : 0;
}

// ---------------------------------------------------------------------------
// LDS swizzles (16B-granule XOR; fragment reads land 2 lanes/16B-slot = free)
// ---------------------------------------------------------------------------
__device__ __forceinline__ unsigned short* stg(unsigned short* buf, int r, int u) {
  return buf + r * 64 + ((u ^ (r & 7)) << 3);
}
__device__ __forceinline__ const unsigned short* stgc(const unsigned short* buf, int r, int u) {
  return buf + r * 64 + ((u ^ (r & 7)) << 3);
}
__device__ __forceinline__ int sw_idx(int r, int c) {
  return r * 128 + ((((c >> 3) ^ (r & 7)) << 3) | (c & 7));
}

// 16-element (along K) register chunk, stored to LDS as bf16
template <typename T> struct RegChunk;
template <> struct RegChunk<float> {
  float4 v[4];
  __device__ __forceinline__ void load(const float* p) {
    const float4* q = reinterpret_cast<const float4*>(p);
    v[0] = q[0]; v[1] = q[1]; v[2] = q[2]; v[3] = q[3];
  }
  __device__ __forceinline__ void store(unsigned short* d) {  // contiguous
    union { unsigned short u[16]; s16x8 w[2]; } t;
    const float* f = reinterpret_cast<const float*>(v);
#pragma unroll
    for (int i = 0; i < 16; ++i) t.u[i] = f2bf(f[i]);
    reinterpret_cast<s16x8*>(d)[0] = t.w[0];
    reinterpret_cast<s16x8*>(d)[1] = t.w[1];
  }
  __device__ __forceinline__ void store2(unsigned short* d0, unsigned short* d1) {  // swizzled
    union { unsigned short u[16]; s16x8 w[2]; } t;
    const float* f = reinterpret_cast<const float*>(v);
#pragma unroll
    for (int i = 0; i < 16; ++i) t.u[i] = f2bf(f[i]);
    *reinterpret_cast<s16x8*>(d0) = t.w[0];
    *reinterpret_cast<s16x8*>(d1) = t.w[1];
  }
};
template <> struct RegChunk<__hip_bfloat16> {
  s16x8 v[2];
  __device__ __forceinline__ void load(const __hip_bfloat16* p) {
    const s16x8* q = reinterpret_cast<const s16x8*>(p);
    v[0] = q[0]; v[1] = q[1];
  }
  __device__ __forceinline__ void store(unsigned short* d) {
    reinterpret_cast<s16x8*>(d)[0] = v[0];
    reinterpret_cast<s16x8*>(d)[1] = v[1];
  }
  __device__ __forceinline__ void store2(unsigned short* d0, unsigned short* d1) {
    *reinterpret_cast<s16x8*>(d0) = v[0];
    *reinterpret_cast<s16x8*>(d1) = v[1];
  }
};

// ===========================================================================
// NEW PATH
// ===========================================================================

// ---------------------------------------------------------------------------
// k_gemm: 128x128 tile GEMM, 256 thr (4 waves, each 64x64 quadrant), BK=64,
// swizzled reg-staged LDS, 1-deep prefetch. dst = bf16 rowmajor [.. ][dstride].
// MFMA 16x16x32_bf16 layouts (HW-verified):
//   A: m=lane&15, k=quad*8+j ; B: n=lane&15, k=quad*8+j ;
//   D: col=lane&15, row=quad*4+reg
// ---------------------------------------------------------------------------
template <typename T>
__device__ __forceinline__ void gemm_tile(const T* __restrict__ A, const T* __restrict__ W,
                                          const T* __restrict__ bias,
                                          unsigned short* __restrict__ dst, int dstride,
                                          int Mt, int Nt,
                                          unsigned short* Ab, unsigned short* Bb) {
  const int tid = threadIdx.x;
  const int w = tid >> 6, l = tid & 63;
  const int quad = l >> 4, l16 = l & 15;
  const int wr = (w >> 1) * 64, wc = (w & 1) * 64;
  const int sr = tid >> 1, sh = (tid & 1) * 32, u0 = (tid & 1) * 4;

  const T* Asrc = A + ((size_t)(Mt * 128 + sr)) * 512 + sh;
  const T* Wsrc = W + ((size_t)(Nt * 128 + sr)) * 512 + sh;
  unsigned short* ad0 = stg(Ab, sr, u0);
  unsigned short* ad1 = stg(Ab, sr, u0 + 1);
  unsigned short* ad2 = stg(Ab, sr, u0 + 2);
  unsigned short* ad3 = stg(Ab, sr, u0 + 3);
  unsigned short* bd0 = stg(Bb, sr, u0);
  unsigned short* bd1 = stg(Bb, sr, u0 + 1);
  unsigned short* bd2 = stg(Bb, sr, u0 + 2);
  unsigned short* bd3 = stg(Bb, sr, u0 + 3);

  const f32x4 zero4 = {0.f, 0.f, 0.f, 0.f};
  f32x4 acc[4][4];
#pragma unroll
  for (int i = 0; i < 4; ++i)
#pragma unroll
    for (int j = 0; j < 4; ++j) acc[i][j] = zero4;

  RegChunk<T> ra0, ra1, rb0, rb1;
  ra0.load(Asrc);
  ra1.load(Asrc + 16);
  rb0.load(Wsrc);
  rb1.load(Wsrc + 16);

#pragma unroll
  for (int k0 = 0; k0 < 512; k0 += 64) {
    __syncthreads();
    ra0.store2(ad0, ad1);
    ra1.store2(ad2, ad3);
    rb0.store2(bd0, bd1);
    rb1.store2(bd2, bd3);
    if (k0 + 64 < 512) {
      ra0.load(Asrc + k0 + 64);
      ra1.load(Asrc + k0 + 80);
      rb0.load(Wsrc + k0 + 64);
      rb1.load(Wsrc + k0 + 80);
    }
    __syncthreads();
#pragma unroll
    for (int kk2 = 0; kk2 < 2; ++kk2) {
      s16x8 af[4], bfr[4];
#pragma unroll
      for (int i = 0; i < 4; ++i)
        af[i] = *reinterpret_cast<const s16x8*>(stgc(Ab, wr + i * 16 + l16, kk2 * 4 + quad));
#pragma unroll
      for (int j = 0; j < 4; ++j)
        bfr[j] = *reinterpret_cast<const s16x8*>(stgc(Bb, wc + j * 16 + l16, kk2 * 4 + quad));
#pragma unroll
      for (int i = 0; i < 4; ++i)
#pragma unroll
        for (int j = 0; j < 4; ++j) acc[i][j] = mfma16(af[i], bfr[j], acc[i][j]);
    }
  }

#pragma unroll
  for (int j = 0; j < 4; ++j) {
    float bb = tofl(bias[Nt * 128 + wc + j * 16 + l16]);
#pragma unroll
    for (int i = 0; i < 4; ++i)
#pragma unroll
      for (int rg = 0; rg < 4; ++rg) {
        int row = Mt * 128 + wr + i * 16 + quad * 4 + rg;
        int col = Nt * 128 + wc + j * 16 + l16;
        dst[(size_t)row * dstride + col] = f2bf(acc[i][j][rg] + bb);
      }
  }
}

template <typename T>
__device__ __forceinline__ void gemm_dispatch(const T* inputs, const T* queries,
                                              const T* Wkv, const T* Wq, const T* bkv,
                                              const T* bq, unsigned short* kv,
                                              unsigned short* qws, unsigned short* Ab,
                                              unsigned short* Bb) {
  // XCD-bijective swizzle (2056 = 8*257): all 8 Nt-blocks of one Mt-panel land
  // on the same XCD in the same scheduling window -> A-panel L2 reuse.
  const int bid = blockIdx.x;
  const int t = (bid & 7) * 257 + (bid >> 3);
  if (t < 2048) {
    gemm_tile<T>(inputs, Wkv, bkv, kv, 1024, t >> 3, t & 7, Ab, Bb);
  } else {
    const int tq = t - 2048;
    gemm_tile<T>(queries, Wq, bq, qws, 512, tq >> 2, tq & 3, Ab, Bb);
  }
}

__global__ __launch_bounds__(256) void k_gemm(const void* inputs, const void* queries,
                                              const void* Wkv, const void* Wq,
                                              const void* bkv, const void* bq,
                                              unsigned short* kv, unsigned short* qws) {
  __shared__ unsigned short Ab[128 * 64];  // 16 KiB
  __shared__ unsigned short Bb[128 * 64];  // 16 KiB
  if (detect_fp32((const unsigned short*)inputs))
    gemm_dispatch<float>((const float*)inputs, (const float*)queries, (const float*)Wkv,
                         (const float*)Wq, (const float*)bkv, (const float*)bq, kv, qws, Ab,
                         Bb);
  else
    gemm_dispatch<__hip_bfloat16>((const __hip_bfloat16*)inputs,
                                  (const __hip_bfloat16*)queries,
                                  (const __hip_bfloat16*)Wkv, (const __hip_bfloat16*)Wq,
                                  (const __hip_bfloat16*)bkv, (const __hip_bfloat16*)bq, kv,
                                  qws, Ab, Bb);
}

// ---------------------------------------------------------------------------
// k_attn: grid (32 stile, 8 b), 512 thr. Per head-pair hpi: stage K-tile
// [128s][128d] and V^T [128d][128s] from kv, then R1-verified u-GEMM/P/den +
// num-GEMM. Partials out (no atomics).
// ---------------------------------------------------------------------------
template <typename T>
__device__ __forceinline__ void attn_body(const unsigned short* __restrict__ kv,
                                          const unsigned short* __restrict__ qws,
                                          const T* __restrict__ masks,
                                          float* __restrict__ num_part,
                                          float* __restrict__ den_part,
                                          unsigned short* kvb, unsigned short* vtb,
                                          unsigned short* Pb, float* denL) {
  const int stile = blockIdx.x, b = blockIdx.y;
  const int s0 = stile * 128;
  const int tid = threadIdx.x;
  const int w = tid >> 6, l = tid & 63;
  const int quad = l >> 4, l16 = l & 15;
  const int hh = w >> 2, mt = (w >> 1) & 1, sh = w & 1, dh = w & 1;
  const int sr2 = tid >> 2, c0 = (tid & 3) * 32;
  const f32x4 zero4 = {0.f, 0.f, 0.f, 0.f};
  const float scale = 0.044194173824159216f;  // 1/sqrt(512)
  const int bstile = b * 32 + stile;

  for (int hpi = 0; hpi < 4; ++hpi) {
    // ---- stage K (swizzled rowmajor) and V^T (swizzled transpose) ----
    const unsigned short* kr =
        kv + ((size_t)(b * 4096 + s0 + sr2)) * 1024 + hpi * 128 + c0;
#pragma unroll
    for (int j = 0; j < 4; ++j)
      *reinterpret_cast<s16x8*>(&kvb[sw_idx(sr2, c0 + j * 8)]) =
          *reinterpret_cast<const s16x8*>(kr + j * 8);
    const unsigned short* vr = kr + 512;
#pragma unroll
    for (int j = 0; j < 4; ++j) {
      union { s16x8 wv; unsigned short u[8]; } tv;
      tv.wv = *reinterpret_cast<const s16x8*>(vr + j * 8);
#pragma unroll
      for (int e = 0; e < 8; ++e) vtb[sw_idx(c0 + j * 8 + e, sr2)] = tv.u[e];
    }
    __syncthreads();

    // ---- u-GEMM + P + denL: wave -> (hh, mt, sh) ----
    {
      f32x4 ua[4];
#pragma unroll
      for (int j = 0; j < 4; ++j) ua[j] = zero4;
#pragma unroll
      for (int kk = 0; kk < 2; ++kk) {
        s16x8 aq = *reinterpret_cast<const s16x8*>(
            &qws[((size_t)(b * 32 + mt * 16 + l16)) * 512 + hpi * 128 + hh * 64 + kk * 32 +
                 quad * 8]);
#pragma unroll
        for (int j = 0; j < 4; ++j) {
          s16x8 bk = *reinterpret_cast<const s16x8*>(
              &kvb[sw_idx(sh * 64 + j * 16 + l16, hh * 64 + kk * 32 + quad * 8)]);
          ua[j] = mfma16(aq, bk, ua[j]);
        }
      }
      float dsum[4] = {0.f, 0.f, 0.f, 0.f};
#pragma unroll
      for (int j = 0; j < 4; ++j) {
        int scol = sh * 64 + j * 16 + l16;
        float mask = tofl(masks[(size_t)b * 4096 + s0 + scol]);
#pragma unroll
        for (int rg = 0; rg < 4; ++rg) {
          int qrow = mt * 16 + quad * 4 + rg;
          float uv = ua[j][rg] * scale;
          float e = uv > 0.f ? uv : (__expf(uv) - 1.f);  // elu (low clip dead)
          e = fminf(e, 15.f);
          float p = __expf(e) * mask;
          unsigned short pu = f2bf(p);
          Pb[sw_idx(hh * 32 + qrow, scol)] = pu;
          dsum[rg] += bf2f(pu);  // sum the ROUNDED value num-GEMM uses
        }
      }
#pragma unroll
      for (int rg = 0; rg < 4; ++rg) {
        float s = dsum[rg];
        s += __shfl_xor(s, 1);
        s += __shfl_xor(s, 2);
        s += __shfl_xor(s, 4);
        s += __shfl_xor(s, 8);
        if (l16 == 0) denL[sh * 64 + hh * 32 + mt * 16 + quad * 4 + rg] = s;
      }
    }
    __syncthreads();  // Pb + denL complete

    // ---- den_part store (both s-halves combined) ----
    if (tid < 64) {
      int qrow = tid & 31, hd = tid >> 5;
      den_part[((size_t)bstile * 32 + qrow) * 8 + hpi * 2 + hd] =
          denL[hd * 32 + qrow] + denL[64 + hd * 32 + qrow];
    }

    // ---- num-GEMM: wave -> (hh, mt, dh) ----
    {
      f32x4 na0 = zero4, na1 = zero4;
#pragma unroll
      for (int kk = 0; kk < 4; ++kk) {
        s16x8 ap = *reinterpret_cast<const s16x8*>(
            &Pb[sw_idx(hh * 32 + mt * 16 + l16, kk * 32 + quad * 8)]);
        s16x8 bv0 = *reinterpret_cast<const s16x8*>(
            &vtb[sw_idx(hh * 64 + dh * 32 + l16, kk * 32 + quad * 8)]);
        s16x8 bv1 = *reinterpret_cast<const s16x8*>(
            &vtb[sw_idx(hh * 64 + dh * 32 + 16 + l16, kk * 32 + quad * 8)]);
        na0 = mfma16(ap, bv0, na0);
        na1 = mfma16(ap, bv1, na1);
      }
#pragma unroll
      for (int rg = 0; rg < 4; ++rg) {
        int qrow = mt * 16 + quad * 4 + rg;
        size_t base = ((size_t)bstile * 32 + qrow) * 512 + (hpi * 2 + hh) * 64 + dh * 32;
        num_part[base + l16] = na0[rg];
        num_part[base + 16 + l16] = na1[rg];
      }
    }
    __syncthreads();  // before next hpi overwrites kvb/vtb/Pb/denL
  }
}

__global__ __launch_bounds__(512) void k_attn(const unsigned short* __restrict__ kv,
                                              const unsigned short* __restrict__ qws,
                                              const void* masks, float* __restrict__ num_part,
                                              float* __restrict__ den_part,
                                              const unsigned short* __restrict__ det) {
  __shared__ unsigned short kvb[128 * 128];  // 32 KiB
  __shared__ unsigned short vtb[128 * 128];  // 32 KiB
  __shared__ unsigned short Pb[64 * 128];    // 16 KiB
  __shared__ float denL[128];
  if (detect_fp32(det))
    attn_body<float>(kv, qws, (const float*)masks, num_part, den_part, kvb, vtb, Pb, denL);
  else
    attn_body<__hip_bfloat16>(kv, qws, (const __hip_bfloat16*)masks, num_part, den_part,
                              kvb, vtb, Pb, denL);
}

// ---------------------------------------------------------------------------
__global__ __launch_bounds__(256) void k_final(const float* __restrict__ num_part,
                                               const float* __restrict__ den_part, void* out,
                                               const unsigned short* __restrict__ det) {
  int i = blockIdx.x * 256 + threadIdx.x;
  int b = i >> 14, qhd = i & 16383;
  int q = (i >> 9) & 31, h = (i >> 6) & 7;
  float sn = 0.f, sd = 0.f;
#pragma unroll 4
  for (int st = 0; st < 32; ++st) {
    sn += num_part[(((size_t)(b * 32 + st)) << 14) + qhd];
    sd += den_part[((size_t)(b * 32 + st) * 32 + q) * 8 + h];
  }
  float v = sn / sd;
  if (detect_fp32(det))
    ((float*)out)[i] = v;
  else
    ((__hip_bfloat16*)out)[i] = __float2bfloat16(v);
}

// ===========================================================================
// FALLBACK PATH (R1-verified, 231 us) — used only if ws is too small.
// ===========================================================================
template <typename T>
__device__ __forceinline__ void qproj_body_fb(const T* __restrict__ queries,
                                              const T* __restrict__ Wq,
                                              const T* __restrict__ bq,
                                              unsigned short* __restrict__ qws,
                                              unsigned short* Abuf, unsigned short* Bbuf) {
  const int Mt = blockIdx.x, Nt = blockIdx.y;
  const int tid = threadIdx.x;
  const int w = tid >> 6, l = tid & 63;
  const int quad = l >> 4, l16 = l & 15;
  const int wr = (w >> 1) * 64, wc = (w & 1) * 64;
  const int r_st = tid >> 1;
  const int kk_st = (tid & 1) * 16;
  const T* Asrc = queries + ((size_t)(Mt * 128 + r_st)) * 512 + kk_st;
  const T* Bsrc = Wq + ((size_t)(Nt * 128 + r_st)) * 512 + kk_st;

  const f32x4 zero4 = {0.f, 0.f, 0.f, 0.f};
  f32x4 acc[4][4];
#pragma unroll
  for (int i = 0; i < 4; ++i)
#pragma unroll
    for (int j = 0; j < 4; ++j) acc[i][j] = zero4;

  RegChunk<T> ra, rb;
  ra.load(Asrc);
  rb.load(Bsrc);
  for (int k0 = 0; k0 < 512; k0 += 32) {
    __syncthreads();
    ra.store(&Abuf[r_st * 32 + kk_st]);
    rb.store(&Bbuf[r_st * 32 + kk_st]);
    if (k0 + 32 < 512) {
      ra.load(Asrc + k0 + 32);
      rb.load(Bsrc + k0 + 32);
    }
    __syncthreads();
    s16x8 af[4], bfr[4];
#pragma unroll
    for (int i = 0; i < 4; ++i)
      af[i] = *reinterpret_cast<const s16x8*>(&Abuf[(wr + i * 16 + l16) * 32 + quad * 8]);
#pragma unroll
    for (int j = 0; j < 4; ++j)
      bfr[j] = *reinterpret_cast<const s16x8*>(&Bbuf[(wc + j * 16 + l16) * 32 + quad * 8]);
#pragma unroll
    for (int i = 0; i < 4; ++i)
#pragma unroll
      for (int j = 0; j < 4; ++j) acc[i][j] = mfma16(af[i], bfr[j], acc[i][j]);
  }
#pragma unroll
  for (int j = 0; j < 4; ++j) {
    float bb = tofl(bq[Nt * 128 + wc + j * 16 + l16]);
#pragma unroll
    for (int i = 0; i < 4; ++i)
#pragma unroll
      for (int rg = 0; rg < 4; ++rg) {
        int row = Mt * 128 + wr + i * 16 + quad * 4 + rg;
        int col = Nt * 128 + wc + j * 16 + l16;
        qws[(size_t)row * 512 + col] = f2bf(acc[i][j][rg] + bb);
      }
  }
}

__global__ __launch_bounds__(256) void k_qproj_fb(const void* queries, const void* Wq,
                                                  const void* bq, unsigned short* qws,
                                                  const unsigned short* __restrict__ det) {
  __shared__ unsigned short Abuf[128 * 32];
  __shared__ unsigned short Bbuf[128 * 32];
  if (detect_fp32(det))
    qproj_body_fb<float>((const float*)queries, (const float*)Wq, (const float*)bq, qws,
                         Abuf, Bbuf);
  else
    qproj_body_fb<__hip_bfloat16>((const __hip_bfloat16*)queries,
                                  (const __hip_bfloat16*)Wq, (const __hip_bfloat16*)bq, qws,
                                  Abuf, Bbuf);
}

template <typename T>
__device__ __forceinline__ void fused_body_fb(
    const T* __restrict__ inputs, const T* __restrict__ masks, const T* __restrict__ Wkv,
    const T* __restrict__ bkv, const unsigned short* __restrict__ qws,
    float* __restrict__ num, float* __restrict__ den, unsigned short* Abuf,
    unsigned short* Bbuf, unsigned short* kvbuf, unsigned short* vbuf,
    unsigned short* Pbuf) {
  const int stile = blockIdx.x;
  const int b = blockIdx.y;
  const int hp = blockIdx.z;
  const int s0 = stile * 128;
  const int tid = threadIdx.x;
  const int w = tid >> 6;
  const int l = tid & 63;
  const int quad = l >> 4;
  const int l16 = l & 15;
  const int which = w >> 2;
  const int wr = ((w >> 1) & 1) * 64;
  const int wc = (w & 1) * 64;

  const f32x4 zero4 = {0.f, 0.f, 0.f, 0.f};
  f32x4 acc[4][4];
#pragma unroll
  for (int i = 0; i < 4; ++i)
#pragma unroll
    for (int j = 0; j < 4; ++j) acc[i][j] = zero4;

  const int sr = tid >> 2;
  const int sc = tid & 3;
  const T* Asrc = inputs + ((size_t)(b * 4096 + s0 + sr)) * 512 + sc * 16;
  const T* BKs = Wkv + ((size_t)(hp * 128 + sr)) * 512 + sc * 16;
  const T* BVs = Wkv + ((size_t)(512 + hp * 128 + sr)) * 512 + sc * 16;
  unsigned short* ad0 = stg(Abuf, sr, sc * 2);
  unsigned short* ad1 = stg(Abuf, sr, sc * 2 + 1);
  unsigned short* bk0 = stg(Bbuf, sr, sc * 2);
  unsigned short* bk1 = stg(Bbuf, sr, sc * 2 + 1);
  unsigned short* bv0 = stg(Bbuf, 128 + sr, sc * 2);
  unsigned short* bv1 = stg(Bbuf, 128 + sr, sc * 2 + 1);

  RegChunk<T> ra0, ra1, rbk, rbv;
  ra0.load(Asrc);
  ra1.load(Asrc + 64);
  rbk.load(BKs);
  rbv.load(BVs);

#pragma unroll
  for (int it2 = 0; it2 < 4; ++it2) {
#pragma unroll
    for (int ph = 0; ph < 2; ++ph) {
      const int it = it2 * 2 + ph;
      RegChunk<T>& ra = ph ? ra1 : ra0;
      __syncthreads();
      ra.store2(ad0, ad1);
      rbk.store2(bk0, bk1);
      rbv.store2(bv0, bv1);
      if (it < 6) ra.load(Asrc + (it + 2) * 64);
      if (it < 7) {
        rbk.load(BKs + (it + 1) * 64);
        rbv.load(BVs + (it + 1) * 64);
      }
      __syncthreads();
#pragma unroll
      for (int kk2 = 0; kk2 < 2; ++kk2) {
        s16x8 af[4], bfr[4];
#pragma unroll
        for (int i = 0; i < 4; ++i)
          af[i] = *reinterpret_cast<const s16x8*>(stgc(Abuf, wr + i * 16 + l16, kk2 * 4 + quad));
#pragma unroll
        for (int j = 0; j < 4; ++j)
          bfr[j] = *reinterpret_cast<const s16x8*>(
              stgc(Bbuf, which * 128 + wc + j * 16 + l16, kk2 * 4 + quad));
#pragma unroll
        for (int i = 0; i < 4; ++i)
#pragma unroll
          for (int j = 0; j < 4; ++j) acc[i][j] = mfma16(af[i], bfr[j], acc[i][j]);
      }
    }
  }

#pragma unroll
  for (int j = 0; j < 4; ++j) {
    float bb = tofl(bkv[which * 512 + hp * 128 + wc + j * 16 + l16]);
#pragma unroll
    for (int i = 0; i < 4; ++i)
#pragma unroll
      for (int rg = 0; rg < 4; ++rg) {
        int sl = wr + i * 16 + quad * 4 + rg;
        int c = wc + j * 16 + l16;
        unsigned short bv = f2bf(acc[i][j][rg] + bb);
        if (which == 0)
          kvbuf[sw_idx(sl, c)] = bv;
        else
          vbuf[sw_idx(c, sl)] = bv;
      }
  }
  __syncthreads();

  const int hh = w >> 2, mt = (w >> 1) & 1, sh = w & 1;
  {
    f32x4 ua[4];
#pragma unroll
    for (int j = 0; j < 4; ++j) ua[j] = zero4;
#pragma unroll
    for (int kk = 0; kk < 2; ++kk) {
      s16x8 aq = *reinterpret_cast<const s16x8*>(
          qws + ((size_t)(b * 32 + mt * 16 + l16)) * 512 + hp * 128 + hh * 64 + kk * 32 +
          quad * 8);
#pragma unroll
      for (int j = 0; j < 4; ++j) {
        s16x8 bk = *reinterpret_cast<const s16x8*>(
            &kvbuf[sw_idx(sh * 64 + j * 16 + l16, hh * 64 + kk * 32 + quad * 8)]);
        ua[j] = mfma16(aq, bk, ua[j]);
      }
    }
    const float scale = 0.044194173824159216f;
    float dsum[4] = {0.f, 0.f, 0.f, 0.f};
#pragma unroll
    for (int j = 0; j < 4; ++j) {
      int scol = sh * 64 + j * 16 + l16;
      float mask = tofl(masks[(size_t)b * 4096 + s0 + scol]);
#pragma unroll
      for (int rg = 0; rg < 4; ++rg) {
        int qrow = mt * 16 + quad * 4 + rg;
        float uv = ua[j][rg] * scale;
        float e = uv > 0.f ? uv : (__expf(uv) - 1.f);
        e = fminf(e, 15.f);
        float p = __expf(e) * mask;
        unsigned short pu = f2bf(p);
        Pbuf[sw_idx(hh * 32 + qrow, scol)] = pu;
        dsum[rg] += bf2f(pu);
      }
    }
#pragma unroll
    for (int rg = 0; rg < 4; ++rg) {
      float s = dsum[rg];
      s += __shfl_xor(s, 1);
      s += __shfl_xor(s, 2);
      s += __shfl_xor(s, 4);
      s += __shfl_xor(s, 8);
      if (l16 == 0) {
        int qrow = mt * 16 + quad * 4 + rg;
        atomicAdd(&den[((size_t)(b * 32 + qrow)) * 8 + hp * 2 + hh], s);
      }
    }
  }
  __syncthreads();

  {
    const int dh = w & 1;
    f32x4 na[2];
    na[0] = zero4;
    na[1] = zero4;
#pragma unroll
    for (int kk = 0; kk < 4; ++kk) {
      s16x8 ap = *reinterpret_cast<const s16x8*>(
          &Pbuf[sw_idx(hh * 32 + mt * 16 + l16, kk * 32 + quad * 8)]);
#pragma unroll
      for (int jj = 0; jj < 2; ++jj) {
        int j = dh * 2 + jj;
        s16x8 bv = *reinterpret_cast<const s16x8*>(
            &vbuf[sw_idx(hh * 64 + j * 16 + l16, kk * 32 + quad * 8)]);
        na[jj] = mfma16(ap, bv, na[jj]);
      }
    }
    const int h = hp * 2 + hh;
#pragma unroll
    for (int jj = 0; jj < 2; ++jj) {
      int d = (dh * 2 + jj) * 16 + l16;
#pragma unroll
      for (int rg = 0; rg < 4; ++rg) {
        int qrow = mt * 16 + quad * 4 + rg;
        atomicAdd(&num[(((size_t)(b * 32 + qrow)) * 8 + h) * 64 + d], na[jj][rg]);
      }
    }
  }
}

__global__ __launch_bounds__(512, 2) void k_fused_fb(const void* inputs, const void* masks,
                                                     const void* Wkv, const void* bkv,
                                                     const unsigned short* __restrict__ qws,
                                                     float* __restrict__ num,
                                                     float* __restrict__ den) {
  __shared__ unsigned short Abuf[128 * 64];
  __shared__ unsigned short Bbuf[256 * 64];
  __shared__ unsigned short kvbuf[128 * 128];
  __shared__ unsigned short vbuf[128 * 128];
  __shared__ unsigned short Pbuf[64 * 128];
  if (detect_fp32((const unsigned short*)inputs))
    fused_body_fb<float>((const float*)inputs, (const float*)masks, (const float*)Wkv,
                         (const float*)bkv, qws, num, den, Abuf, Bbuf, kvbuf, vbuf, Pbuf);
  else
    fused_body_fb<__hip_bfloat16>((const __hip_bfloat16*)inputs,
                                  (const __hip_bfloat16*)masks, (const __hip_bfloat16*)Wkv,
                                  (const __hip_bfloat16*)bkv, qws, num, den, Abuf, Bbuf,
                                  kvbuf, vbuf, Pbuf);
}

__global__ __launch_bounds__(256) void k_div_fb(const float* __restrict__ num,
                                                const float* __restrict__ den, void* out,
                                                const unsigned short* __restrict__ det) {
  int i = blockIdx.x * 256 + threadIdx.x;
  float v = num[i] / den[i >> 6];
  if (detect_fp32(det))
    ((float*)out)[i] = v;
  else
    ((__hip_bfloat16*)out)[i] = __float2bfloat16(v);
}

// ---------------------------------------------------------------------------
extern "C" void kernel_launch(void* const* d_in, const int* in_sizes, int n_in,
                              void* d_out, int out_size, void* d_ws, size_t ws_size,
                              hipStream_t stream) {
  // d_in: 0 inputs, 1 queries, 2 masks, 3 Wkv, 4 bkv, 5 Wq, 6 bq
  char* ws = (char*)d_ws;
  if (ws_size >= 84410368) {
    // NEW path. ws: [0] qws 256K ; [256K] kv 64M ; [67371008] num_part 16M ;
    //           [84148224] den_part 256K
    unsigned short* qws = (unsigned short*)ws;
    unsigned short* kv = (unsigned short*)(ws + 262144);
    float* num_part = (float*)(ws + 67371008);
    float* den_part = (float*)(ws + 84148224);

    k_gemm<<<2056, 256, 0, stream>>>(d_in[0], d_in[1], d_in[3], d_in[5], d_in[4], d_in[6],
                                     kv, qws);
    k_attn<<<dim3(32, 8), 512, 0, stream>>>(kv, qws, d_in[2], num_part, den_part,
                                            (const unsigned short*)d_in[0]);
    k_final<<<512, 256, 0, stream>>>(num_part, den_part, d_out,
                                     (const unsigned short*)d_in[0]);
  } else if (ws_size >= 802816) {
    // FALLBACK (R1 path). ws: [1024] den ; [16384] num ; [540672] qws
    float* den = (float*)(ws + 1024);
    float* num = (float*)(ws + 16384);
    unsigned short* qws = (unsigned short*)(ws + 540672);

    hipMemsetAsync(d_ws, 0, 540672, stream);
    dim3 gq(2, 4);
    k_qproj_fb<<<gq, 256, 0, stream>>>(d_in[1], d_in[5], d_in[6], qws,
                                       (const unsigned short*)d_in[0]);
    dim3 g2(32, 8, 4);
    k_fused_fb<<<g2, 512, 0, stream>>>(d_in[0], d_in[2], d_in[3], d_in[4], qws, num, den);
    k_div_fb<<<512, 256, 0, stream>>>(num, den, d_out, (const unsigned short*)d_in[0]);
  }
}

// Round 6
// 182.377 us; speedup vs baseline: 2.0207x; 1.5149x over previous
//
#include <hip/hip_runtime.h>
#include <hip/hip_bf16.h>

// ---------------------------------------------------------------------------
// MultiHeadAttention for MI355X (gfx950)
// B=8 S=4096 Q=32 H=8 D=64 IN=512 NKV=1024
// R10: 4 regular dispatches:
//   k_conv : convert ALL inputs to one contiguous bf16 region in ws
//            (dtype-uniform downstream; ~106 MB streaming).
//   k_gemm2: bf16-only 128x128 GEMM, BK=64, __builtin_amdgcn_global_load_lds
//            (m97 structure: linear LDS dest + inverse-swizzled global src,
//            2 barriers/K-step, 32 KiB LDS, no staging VGPRs -> ~4 blocks/CU).
//            Writes kv[32768][1024] and qws[256][512].
//   k_attn : 256 blocks, attention math (R1-verified), per-block partials.
//   k_final: reduce 32 partials + divide.
// Fallback: R1-verified 3-kernel path if ws_size < 120 MB.
// ---------------------------------------------------------------------------

typedef float f32x4 __attribute__((ext_vector_type(4)));
typedef short s16x8 __attribute__((ext_vector_type(8)));

__device__ __forceinline__ unsigned short f2bf(float f) {
  union { __hip_bfloat16 h; unsigned short u; } cv;
  cv.h = __float2bfloat16(f);
  return cv.u;
}
__device__ __forceinline__ float bf2f(unsigned short u) {
  union { unsigned short u; __hip_bfloat16 h; } cv;
  cv.u = u;
  return __bfloat162float(cv.h);
}
__device__ __forceinline__ float tofl(float v) { return v; }
__device__ __forceinline__ float tofl(__hip_bfloat16 v) { return __bfloat162float(v); }

__device__ __forceinline__ f32x4 mfma16(s16x8 a, s16x8 b, f32x4 c) {
  return __builtin_amdgcn_mfma_f32_16x16x32_bf16(a, b, c, 0, 0, 0);
}

// dtype detection (1 = fp32, 0 = bf16)
__device__ __forceinline__ int detect_fp32(const unsigned short* __restrict__ in16) {
  unsigned short v = in16[2 * (threadIdx.x & 63)];
  int e = (v >> 7) & 0xFF;
  unsigned long long m = __ballot(e >= 100 && e <= 130);
  return __popcll(m) < 48 ? 1 : 0;
}

// direct global->LDS 16B (per-lane gptr, wave-uniform LDS base; HW scatters
// lane i -> base + i*16B)
__device__ __forceinline__ void gload_lds16(const void* g, void* s) {
  __builtin_amdgcn_global_load_lds(
      (const __attribute__((address_space(1))) unsigned int*)(g),
      (__attribute__((address_space(3))) unsigned int*)(s), 16, 0, 0);
}

// ---------------------------------------------------------------------------
// LDS swizzles (16B-granule XOR over 8-granule (128 B) rows)
// ---------------------------------------------------------------------------
__device__ __forceinline__ unsigned short* stg(unsigned short* buf, int r, int u) {
  return buf + r * 64 + ((u ^ (r & 7)) << 3);
}
__device__ __forceinline__ const unsigned short* stgc(const unsigned short* buf, int r, int u) {
  return buf + r * 64 + ((u ^ (r & 7)) << 3);
}
__device__ __forceinline__ int sw_idx(int r, int c) {
  return r * 128 + ((((c >> 3) ^ (r & 7)) << 3) | (c & 7));
}

// 8-element bf16 fragment load from global (with fp32->bf16 convert)
template <typename T>
__device__ __forceinline__ s16x8 load_frag8(const T* p);
template <>
__device__ __forceinline__ s16x8 load_frag8<float>(const float* p) {
  const float4* q = reinterpret_cast<const float4*>(p);
  float4 a = q[0], b = q[1];
  union { unsigned short u[8]; s16x8 w; } t;
  t.u[0] = f2bf(a.x); t.u[1] = f2bf(a.y); t.u[2] = f2bf(a.z); t.u[3] = f2bf(a.w);
  t.u[4] = f2bf(b.x); t.u[5] = f2bf(b.y); t.u[6] = f2bf(b.z); t.u[7] = f2bf(b.w);
  return t.w;
}
template <>
__device__ __forceinline__ s16x8 load_frag8<__hip_bfloat16>(const __hip_bfloat16* p) {
  return *reinterpret_cast<const s16x8*>(p);
}

// 16-element (along K) register chunk, for the fallback path
template <typename T> struct RegChunk;
template <> struct RegChunk<float> {
  float4 v[4];
  __device__ __forceinline__ void load(const float* p) {
    const float4* q = reinterpret_cast<const float4*>(p);
    v[0] = q[0]; v[1] = q[1]; v[2] = q[2]; v[3] = q[3];
  }
  __device__ __forceinline__ void store(unsigned short* d) {
    union { unsigned short u[16]; s16x8 w[2]; } t;
    const float* f = reinterpret_cast<const float*>(v);
#pragma unroll
    for (int i = 0; i < 16; ++i) t.u[i] = f2bf(f[i]);
    reinterpret_cast<s16x8*>(d)[0] = t.w[0];
    reinterpret_cast<s16x8*>(d)[1] = t.w[1];
  }
  __device__ __forceinline__ void store2(unsigned short* d0, unsigned short* d1) {
    union { unsigned short u[16]; s16x8 w[2]; } t;
    const float* f = reinterpret_cast<const float*>(v);
#pragma unroll
    for (int i = 0; i < 16; ++i) t.u[i] = f2bf(f[i]);
    *reinterpret_cast<s16x8*>(d0) = t.w[0];
    *reinterpret_cast<s16x8*>(d1) = t.w[1];
  }
};
template <> struct RegChunk<__hip_bfloat16> {
  s16x8 v[2];
  __device__ __forceinline__ void load(const __hip_bfloat16* p) {
    const s16x8* q = reinterpret_cast<const s16x8*>(p);
    v[0] = q[0]; v[1] = q[1];
  }
  __device__ __forceinline__ void store(unsigned short* d) {
    reinterpret_cast<s16x8*>(d)[0] = v[0];
    reinterpret_cast<s16x8*>(d)[1] = v[1];
  }
  __device__ __forceinline__ void store2(unsigned short* d0, unsigned short* d1) {
    *reinterpret_cast<s16x8*>(d0) = v[0];
    *reinterpret_cast<s16x8*>(d1) = v[1];
  }
};

// ===========================================================================
// NEW PATH
// ===========================================================================

// conv region element offsets (bf16 elems)
#define CINP 0
#define CQ   16777216
#define CWKV 16908288
#define CWQ  17432576
#define CBKV 17694720
#define CBQ  17695744
#define CTOT 17696256

// ---------------------------------------------------------------------------
// k_conv: convert everything to bf16 into one contiguous ws region.
// 2048 blocks x 256 thr, grid-stride over 8-elem units.
// ---------------------------------------------------------------------------
__global__ __launch_bounds__(256) void k_conv(const void* inputs, const void* queries,
                                              const void* Wkv, const void* Wq,
                                              const void* bkv, const void* bq,
                                              unsigned short* __restrict__ dst) {
  const int fp32 = detect_fp32((const unsigned short*)inputs);
  size_t i8 = (size_t)blockIdx.x * 256 + threadIdx.x;
  const size_t total8 = CTOT / 8;
  for (; i8 < total8; i8 += (size_t)2048 * 256) {
    size_t e = i8 * 8;
    const void* src;
    size_t off;
    if (e < CQ) { src = inputs; off = e - CINP; }
    else if (e < CWKV) { src = queries; off = e - CQ; }
    else if (e < CWQ) { src = Wkv; off = e - CWKV; }
    else if (e < CBKV) { src = Wq; off = e - CWQ; }
    else if (e < CBQ) { src = bkv; off = e - CBKV; }
    else { src = bq; off = e - CBQ; }
    s16x8 v;
    if (fp32)
      v = load_frag8<float>((const float*)src + off);
    else
      v = load_frag8<__hip_bfloat16>((const __hip_bfloat16*)src + off);
    *reinterpret_cast<s16x8*>(dst + e) = v;
  }
}

// ---------------------------------------------------------------------------
// k_gemm2: bf16 128x128-tile GEMM via global_load_lds (m97 structure).
// 256 thr (4 waves, 64x64 quadrants), BK=64, single-buffered 32 KiB LDS,
// 2 barriers/K-step. LDS linear [128][64]; global source granule
// pre-swizzled by (row&7) so swizzled ds_read_b128 is conflict-free.
// MFMA 16x16x32_bf16 layouts (HW-verified):
//   A: m=lane&15, k=quad*8+j ; B: n=lane&15, k=quad*8+j ;
//   D: col=lane&15, row=quad*4+reg
// ---------------------------------------------------------------------------
__global__ __launch_bounds__(256) void k_gemm2(const unsigned short* __restrict__ c,
                                               unsigned short* __restrict__ kv,
                                               unsigned short* __restrict__ qws) {
  __shared__ unsigned short Ab[128 * 64];  // 16 KiB
  __shared__ unsigned short Bb[128 * 64];  // 16 KiB

  // XCD-bijective swizzle (2056 = 8*257): consecutive t on one XCD ->
  // the 8 Nt-blocks of an Mt-panel share the A-panel in that XCD's L2.
  const int bid = blockIdx.x;
  const int t = (bid & 7) * 257 + (bid >> 3);
  const unsigned short *A, *W, *bias;
  unsigned short* dst;
  int dstride, Mt, Nt;
  if (t < 2048) {
    A = c + CINP; W = c + CWKV; bias = c + CBKV;
    dst = kv; dstride = 1024; Mt = t >> 3; Nt = t & 7;
  } else {
    const int tq = t - 2048;
    A = c + CQ; W = c + CWQ; bias = c + CBQ;
    dst = qws; dstride = 512; Mt = tq >> 2; Nt = tq & 3;
  }

  const int tid = threadIdx.x;
  const int w = tid >> 6, l = tid & 63;
  const int quad = l >> 4, l16 = l & 15;
  const int wr = (w >> 1) * 64, wc = (w & 1) * 64;

  // global_load_lds lane mapping: lane l -> LDS base + l*16B, i.e. row
  // lrow=l>>3, granule lg=l&7 of an 8-row chunk. Source granule is
  // pre-swizzled: gsw = lg ^ (row&7) = lg ^ lrow (chunk base row % 8 == 0).
  const int lrow = l >> 3;
  const int gsw = (l & 7) ^ lrow;

  const f32x4 zero4 = {0.f, 0.f, 0.f, 0.f};
  f32x4 acc[4][4];
#pragma unroll
  for (int i = 0; i < 4; ++i)
#pragma unroll
    for (int j = 0; j < 4; ++j) acc[i][j] = zero4;

  const size_t arow0 = (size_t)(Mt * 128) * 512;
  const size_t brow0 = (size_t)(Nt * 128) * 512;

#pragma unroll
  for (int k0 = 0; k0 < 512; k0 += 64) {
    __syncthreads();  // previous compute done; LDS free
#pragma unroll
    for (int k = 0; k < 4; ++k) {
      const int row = w * 32 + k * 8 + lrow;          // 0..127
      const int srcc = k0 + gsw * 8;                  // swizzled source col
      gload_lds16(A + arow0 + (size_t)row * 512 + srcc, Ab + (w * 32 + k * 8) * 64);
      gload_lds16(W + brow0 + (size_t)row * 512 + srcc, Bb + (w * 32 + k * 8) * 64);
    }
    __syncthreads();  // implicit vmcnt(0) drain -> tiles resident
#pragma unroll
    for (int kk2 = 0; kk2 < 2; ++kk2) {
      s16x8 af[4], bfr[4];
#pragma unroll
      for (int i = 0; i < 4; ++i)
        af[i] = *reinterpret_cast<const s16x8*>(stgc(Ab, wr + i * 16 + l16, kk2 * 4 + quad));
#pragma unroll
      for (int j = 0; j < 4; ++j)
        bfr[j] = *reinterpret_cast<const s16x8*>(stgc(Bb, wc + j * 16 + l16, kk2 * 4 + quad));
#pragma unroll
      for (int i = 0; i < 4; ++i)
#pragma unroll
        for (int j = 0; j < 4; ++j) acc[i][j] = mfma16(af[i], bfr[j], acc[i][j]);
    }
  }

#pragma unroll
  for (int j = 0; j < 4; ++j) {
    float bb = bf2f(bias[Nt * 128 + wc + j * 16 + l16]);
#pragma unroll
    for (int i = 0; i < 4; ++i)
#pragma unroll
      for (int rg = 0; rg < 4; ++rg) {
        int row = Mt * 128 + wr + i * 16 + quad * 4 + rg;
        int col = Nt * 128 + wc + j * 16 + l16;
        dst[(size_t)row * dstride + col] = f2bf(acc[i][j][rg] + bb);
      }
  }
}

// ---------------------------------------------------------------------------
// k_attn: grid (32 stile, 8 b), 512 thr. Per head-pair hpi: stage K-tile
// [128s][128d] and V^T [128d][128s] from kv, then u-GEMM/P/den + num-GEMM.
// Partials out (no atomics).
// ---------------------------------------------------------------------------
template <typename T>
__device__ __forceinline__ void attn_body(const unsigned short* __restrict__ kv,
                                          const unsigned short* __restrict__ qws,
                                          const T* __restrict__ masks,
                                          float* __restrict__ num_part,
                                          float* __restrict__ den_part,
                                          unsigned short* kvb, unsigned short* vtb,
                                          unsigned short* Pb, float* denL) {
  const int stile = blockIdx.x, b = blockIdx.y;
  const int s0 = stile * 128;
  const int tid = threadIdx.x;
  const int w = tid >> 6, l = tid & 63;
  const int quad = l >> 4, l16 = l & 15;
  const int hh = w >> 2, mt = (w >> 1) & 1, sh = w & 1, dh = w & 1;
  const int sr2 = tid >> 2, c0 = (tid & 3) * 32;
  const f32x4 zero4 = {0.f, 0.f, 0.f, 0.f};
  const float scale = 0.044194173824159216f;  // 1/sqrt(512)
  const int bstile = b * 32 + stile;

  for (int hpi = 0; hpi < 4; ++hpi) {
    // ---- stage K (swizzled rowmajor) and V^T (swizzled transpose) ----
    const unsigned short* kr =
        kv + ((size_t)(b * 4096 + s0 + sr2)) * 1024 + hpi * 128 + c0;
#pragma unroll
    for (int j = 0; j < 4; ++j)
      *reinterpret_cast<s16x8*>(&kvb[sw_idx(sr2, c0 + j * 8)]) =
          *reinterpret_cast<const s16x8*>(kr + j * 8);
    const unsigned short* vr = kr + 512;
#pragma unroll
    for (int j = 0; j < 4; ++j) {
      union { s16x8 wv; unsigned short u[8]; } tv;
      tv.wv = *reinterpret_cast<const s16x8*>(vr + j * 8);
#pragma unroll
      for (int e = 0; e < 8; ++e) vtb[sw_idx(c0 + j * 8 + e, sr2)] = tv.u[e];
    }
    __syncthreads();

    // ---- u-GEMM + P + denL: wave -> (hh, mt, sh) ----
    {
      f32x4 ua[4];
#pragma unroll
      for (int j = 0; j < 4; ++j) ua[j] = zero4;
#pragma unroll
      for (int kk = 0; kk < 2; ++kk) {
        s16x8 aq = *reinterpret_cast<const s16x8*>(
            &qws[((size_t)(b * 32 + mt * 16 + l16)) * 512 + hpi * 128 + hh * 64 + kk * 32 +
                 quad * 8]);
#pragma unroll
        for (int j = 0; j < 4; ++j) {
          s16x8 bk = *reinterpret_cast<const s16x8*>(
              &kvb[sw_idx(sh * 64 + j * 16 + l16, hh * 64 + kk * 32 + quad * 8)]);
          ua[j] = mfma16(aq, bk, ua[j]);
        }
      }
      float dsum[4] = {0.f, 0.f, 0.f, 0.f};
#pragma unroll
      for (int j = 0; j < 4; ++j) {
        int scol = sh * 64 + j * 16 + l16;
        float mask = tofl(masks[(size_t)b * 4096 + s0 + scol]);
#pragma unroll
        for (int rg = 0; rg < 4; ++rg) {
          int qrow = mt * 16 + quad * 4 + rg;
          float uv = ua[j][rg] * scale;
          float e = uv > 0.f ? uv : (__expf(uv) - 1.f);  // elu (low clip dead)
          e = fminf(e, 15.f);
          float p = __expf(e) * mask;
          unsigned short pu = f2bf(p);
          Pb[sw_idx(hh * 32 + qrow, scol)] = pu;
          dsum[rg] += bf2f(pu);  // sum the ROUNDED value num-GEMM uses
        }
      }
#pragma unroll
      for (int rg = 0; rg < 4; ++rg) {
        float s = dsum[rg];
        s += __shfl_xor(s, 1);
        s += __shfl_xor(s, 2);
        s += __shfl_xor(s, 4);
        s += __shfl_xor(s, 8);
        if (l16 == 0) denL[sh * 64 + hh * 32 + mt * 16 + quad * 4 + rg] = s;
      }
    }
    __syncthreads();  // Pb + denL complete

    if (tid < 64) {
      int qrow = tid & 31, hd = tid >> 5;
      den_part[((size_t)bstile * 32 + qrow) * 8 + hpi * 2 + hd] =
          denL[hd * 32 + qrow] + denL[64 + hd * 32 + qrow];
    }

    // ---- num-GEMM: wave -> (hh, mt, dh) ----
    {
      f32x4 na0 = zero4, na1 = zero4;
#pragma unroll
      for (int kk = 0; kk < 4; ++kk) {
        s16x8 ap = *reinterpret_cast<const s16x8*>(
            &Pb[sw_idx(hh * 32 + mt * 16 + l16, kk * 32 + quad * 8)]);
        s16x8 bv0 = *reinterpret_cast<const s16x8*>(
            &vtb[sw_idx(hh * 64 + dh * 32 + l16, kk * 32 + quad * 8)]);
        s16x8 bv1 = *reinterpret_cast<const s16x8*>(
            &vtb[sw_idx(hh * 64 + dh * 32 + 16 + l16, kk * 32 + quad * 8)]);
        na0 = mfma16(ap, bv0, na0);
        na1 = mfma16(ap, bv1, na1);
      }
#pragma unroll
      for (int rg = 0; rg < 4; ++rg) {
        int qrow = mt * 16 + quad * 4 + rg;
        size_t base = ((size_t)bstile * 32 + qrow) * 512 + (hpi * 2 + hh) * 64 + dh * 32;
        num_part[base + l16] = na0[rg];
        num_part[base + 16 + l16] = na1[rg];
      }
    }
    __syncthreads();  // before next hpi overwrites kvb/vtb/Pb/denL
  }
}

__global__ __launch_bounds__(512) void k_attn(const unsigned short* __restrict__ kv,
                                              const unsigned short* __restrict__ qws,
                                              const void* masks, float* __restrict__ num_part,
                                              float* __restrict__ den_part,
                                              const unsigned short* __restrict__ det) {
  __shared__ unsigned short kvb[128 * 128];  // 32 KiB
  __shared__ unsigned short vtb[128 * 128];  // 32 KiB
  __shared__ unsigned short Pb[64 * 128];    // 16 KiB
  __shared__ float denL[128];
  if (detect_fp32(det))
    attn_body<float>(kv, qws, (const float*)masks, num_part, den_part, kvb, vtb, Pb, denL);
  else
    attn_body<__hip_bfloat16>(kv, qws, (const __hip_bfloat16*)masks, num_part, den_part,
                              kvb, vtb, Pb, denL);
}

// ---------------------------------------------------------------------------
__global__ __launch_bounds__(256) void k_final(const float* __restrict__ num_part,
                                               const float* __restrict__ den_part, void* out,
                                               const unsigned short* __restrict__ det) {
  int i = blockIdx.x * 256 + threadIdx.x;
  int b = i >> 14, qhd = i & 16383;
  int q = (i >> 9) & 31, h = (i >> 6) & 7;
  float sn = 0.f, sd = 0.f;
#pragma unroll 4
  for (int st = 0; st < 32; ++st) {
    sn += num_part[(((size_t)(b * 32 + st)) << 14) + qhd];
    sd += den_part[((size_t)(b * 32 + st) * 32 + q) * 8 + h];
  }
  float v = sn / sd;
  if (detect_fp32(det))
    ((float*)out)[i] = v;
  else
    ((__hip_bfloat16*)out)[i] = __float2bfloat16(v);
}

// ===========================================================================
// FALLBACK PATH (R1-verified, 231 us) — used only if ws is too small.
// ===========================================================================
template <typename T>
__device__ __forceinline__ void qproj_body_fb(const T* __restrict__ queries,
                                              const T* __restrict__ Wq,
                                              const T* __restrict__ bq,
                                              unsigned short* __restrict__ qws,
                                              unsigned short* Abuf, unsigned short* Bbuf) {
  const int Mt = blockIdx.x, Nt = blockIdx.y;
  const int tid = threadIdx.x;
  const int w = tid >> 6, l = tid & 63;
  const int quad = l >> 4, l16 = l & 15;
  const int wr = (w >> 1) * 64, wc = (w & 1) * 64;
  const int r_st = tid >> 1;
  const int kk_st = (tid & 1) * 16;
  const T* Asrc = queries + ((size_t)(Mt * 128 + r_st)) * 512 + kk_st;
  const T* Bsrc = Wq + ((size_t)(Nt * 128 + r_st)) * 512 + kk_st;

  const f32x4 zero4 = {0.f, 0.f, 0.f, 0.f};
  f32x4 acc[4][4];
#pragma unroll
  for (int i = 0; i < 4; ++i)
#pragma unroll
    for (int j = 0; j < 4; ++j) acc[i][j] = zero4;

  RegChunk<T> ra, rb;
  ra.load(Asrc);
  rb.load(Bsrc);
  for (int k0 = 0; k0 < 512; k0 += 32) {
    __syncthreads();
    ra.store(&Abuf[r_st * 32 + kk_st]);
    rb.store(&Bbuf[r_st * 32 + kk_st]);
    if (k0 + 32 < 512) {
      ra.load(Asrc + k0 + 32);
      rb.load(Bsrc + k0 + 32);
    }
    __syncthreads();
    s16x8 af[4], bfr[4];
#pragma unroll
    for (int i = 0; i < 4; ++i)
      af[i] = *reinterpret_cast<const s16x8*>(&Abuf[(wr + i * 16 + l16) * 32 + quad * 8]);
#pragma unroll
    for (int j = 0; j < 4; ++j)
      bfr[j] = *reinterpret_cast<const s16x8*>(&Bbuf[(wc + j * 16 + l16) * 32 + quad * 8]);
#pragma unroll
    for (int i = 0; i < 4; ++i)
#pragma unroll
      for (int j = 0; j < 4; ++j) acc[i][j] = mfma16(af[i], bfr[j], acc[i][j]);
  }
#pragma unroll
  for (int j = 0; j < 4; ++j) {
    float bb = tofl(bq[Nt * 128 + wc + j * 16 + l16]);
#pragma unroll
    for (int i = 0; i < 4; ++i)
#pragma unroll
      for (int rg = 0; rg < 4; ++rg) {
        int row = Mt * 128 + wr + i * 16 + quad * 4 + rg;
        int col = Nt * 128 + wc + j * 16 + l16;
        qws[(size_t)row * 512 + col] = f2bf(acc[i][j][rg] + bb);
      }
  }
}

__global__ __launch_bounds__(256) void k_qproj_fb(const void* queries, const void* Wq,
                                                  const void* bq, unsigned short* qws,
                                                  const unsigned short* __restrict__ det) {
  __shared__ unsigned short Abuf[128 * 32];
  __shared__ unsigned short Bbuf[128 * 32];
  if (detect_fp32(det))
    qproj_body_fb<float>((const float*)queries, (const float*)Wq, (const float*)bq, qws,
                         Abuf, Bbuf);
  else
    qproj_body_fb<__hip_bfloat16>((const __hip_bfloat16*)queries,
                                  (const __hip_bfloat16*)Wq, (const __hip_bfloat16*)bq, qws,
                                  Abuf, Bbuf);
}

template <typename T>
__device__ __forceinline__ void fused_body_fb(
    const T* __restrict__ inputs, const T* __restrict__ masks, const T* __restrict__ Wkv,
    const T* __restrict__ bkv, const unsigned short* __restrict__ qws,
    float* __restrict__ num, float* __restrict__ den, unsigned short* Abuf,
    unsigned short* Bbuf, unsigned short* kvbuf, unsigned short* vbuf,
    unsigned short* Pbuf) {
  const int stile = blockIdx.x;
  const int b = blockIdx.y;
  const int hp = blockIdx.z;
  const int s0 = stile * 128;
  const int tid = threadIdx.x;
  const int w = tid >> 6;
  const int l = tid & 63;
  const int quad = l >> 4;
  const int l16 = l & 15;
  const int which = w >> 2;
  const int wr = ((w >> 1) & 1) * 64;
  const int wc = (w & 1) * 64;

  const f32x4 zero4 = {0.f, 0.f, 0.f, 0.f};
  f32x4 acc[4][4];
#pragma unroll
  for (int i = 0; i < 4; ++i)
#pragma unroll
    for (int j = 0; j < 4; ++j) acc[i][j] = zero4;

  const int sr = tid >> 2;
  const int sc = tid & 3;
  const T* Asrc = inputs + ((size_t)(b * 4096 + s0 + sr)) * 512 + sc * 16;
  const T* BKs = Wkv + ((size_t)(hp * 128 + sr)) * 512 + sc * 16;
  const T* BVs = Wkv + ((size_t)(512 + hp * 128 + sr)) * 512 + sc * 16;
  unsigned short* ad0 = stg(Abuf, sr, sc * 2);
  unsigned short* ad1 = stg(Abuf, sr, sc * 2 + 1);
  unsigned short* bk0 = stg(Bbuf, sr, sc * 2);
  unsigned short* bk1 = stg(Bbuf, sr, sc * 2 + 1);
  unsigned short* bv0 = stg(Bbuf, 128 + sr, sc * 2);
  unsigned short* bv1 = stg(Bbuf, 128 + sr, sc * 2 + 1);

  RegChunk<T> ra0, ra1, rbk, rbv;
  ra0.load(Asrc);
  ra1.load(Asrc + 64);
  rbk.load(BKs);
  rbv.load(BVs);

#pragma unroll
  for (int it2 = 0; it2 < 4; ++it2) {
#pragma unroll
    for (int ph = 0; ph < 2; ++ph) {
      const int it = it2 * 2 + ph;
      RegChunk<T>& ra = ph ? ra1 : ra0;
      __syncthreads();
      ra.store2(ad0, ad1);
      rbk.store2(bk0, bk1);
      rbv.store2(bv0, bv1);
      if (it < 6) ra.load(Asrc + (it + 2) * 64);
      if (it < 7) {
        rbk.load(BKs + (it + 1) * 64);
        rbv.load(BVs + (it + 1) * 64);
      }
      __syncthreads();
#pragma unroll
      for (int kk2 = 0; kk2 < 2; ++kk2) {
        s16x8 af[4], bfr[4];
#pragma unroll
        for (int i = 0; i < 4; ++i)
          af[i] = *reinterpret_cast<const s16x8*>(stgc(Abuf, wr + i * 16 + l16, kk2 * 4 + quad));
#pragma unroll
        for (int j = 0; j < 4; ++j)
          bfr[j] = *reinterpret_cast<const s16x8*>(
              stgc(Bbuf, which * 128 + wc + j * 16 + l16, kk2 * 4 + quad));
#pragma unroll
        for (int i = 0; i < 4; ++i)
#pragma unroll
          for (int j = 0; j < 4; ++j) acc[i][j] = mfma16(af[i], bfr[j], acc[i][j]);
      }
    }
  }

#pragma unroll
  for (int j = 0; j < 4; ++j) {
    float bb = tofl(bkv[which * 512 + hp * 128 + wc + j * 16 + l16]);
#pragma unroll
    for (int i = 0; i < 4; ++i)
#pragma unroll
      for (int rg = 0; rg < 4; ++rg) {
        int sl = wr + i * 16 + quad * 4 + rg;
        int c = wc + j * 16 + l16;
        unsigned short bv = f2bf(acc[i][j][rg] + bb);
        if (which == 0)
          kvbuf[sw_idx(sl, c)] = bv;
        else
          vbuf[sw_idx(c, sl)] = bv;
      }
  }
  __syncthreads();

  const int hh = w >> 2, mt = (w >> 1) & 1, sh = w & 1;
  {
    f32x4 ua[4];
#pragma unroll
    for (int j = 0; j < 4; ++j) ua[j] = zero4;
#pragma unroll
    for (int kk = 0; kk < 2; ++kk) {
      s16x8 aq = *reinterpret_cast<const s16x8*>(
          qws + ((size_t)(b * 32 + mt * 16 + l16)) * 512 + hp * 128 + hh * 64 + kk * 32 +
          quad * 8);
#pragma unroll
      for (int j = 0; j < 4; ++j) {
        s16x8 bk = *reinterpret_cast<const s16x8*>(
            &kvbuf[sw_idx(sh * 64 + j * 16 + l16, hh * 64 + kk * 32 + quad * 8)]);
        ua[j] = mfma16(aq, bk, ua[j]);
      }
    }
    const float scale = 0.044194173824159216f;
    float dsum[4] = {0.f, 0.f, 0.f, 0.f};
#pragma unroll
    for (int j = 0; j < 4; ++j) {
      int scol = sh * 64 + j * 16 + l16;
      float mask = tofl(masks[(size_t)b * 4096 + s0 + scol]);
#pragma unroll
      for (int rg = 0; rg < 4; ++rg) {
        int qrow = mt * 16 + quad * 4 + rg;
        float uv = ua[j][rg] * scale;
        float e = uv > 0.f ? uv : (__expf(uv) - 1.f);
        e = fminf(e, 15.f);
        float p = __expf(e) * mask;
        unsigned short pu = f2bf(p);
        Pbuf[sw_idx(hh * 32 + qrow, scol)] = pu;
        dsum[rg] += bf2f(pu);
      }
    }
#pragma unroll
    for (int rg = 0; rg < 4; ++rg) {
      float s = dsum[rg];
      s += __shfl_xor(s, 1);
      s += __shfl_xor(s, 2);
      s += __shfl_xor(s, 4);
      s += __shfl_xor(s, 8);
      if (l16 == 0) {
        int qrow = mt * 16 + quad * 4 + rg;
        atomicAdd(&den[((size_t)(b * 32 + qrow)) * 8 + hp * 2 + hh], s);
      }
    }
  }
  __syncthreads();

  {
    const int dh = w & 1;
    f32x4 na[2];
    na[0] = zero4;
    na[1] = zero4;
#pragma unroll
    for (int kk = 0; kk < 4; ++kk) {
      s16x8 ap = *reinterpret_cast<const s16x8*>(
          &Pbuf[sw_idx(hh * 32 + mt * 16 + l16, kk * 32 + quad * 8)]);
#pragma unroll
      for (int jj = 0; jj < 2; ++jj) {
        int j = dh * 2 + jj;
        s16x8 bv = *reinterpret_cast<const s16x8*>(
            &vbuf[sw_idx(hh * 64 + j * 16 + l16, kk * 32 + quad * 8)]);
        na[jj] = mfma16(ap, bv, na[jj]);
      }
    }
    const int h = hp * 2 + hh;
#pragma unroll
    for (int jj = 0; jj < 2; ++jj) {
      int d = (dh * 2 + jj) * 16 + l16;
#pragma unroll
      for (int rg = 0; rg < 4; ++rg) {
        int qrow = mt * 16 + quad * 4 + rg;
        atomicAdd(&num[(((size_t)(b * 32 + qrow)) * 8 + h) * 64 + d], na[jj][rg]);
      }
    }
  }
}

__global__ __launch_bounds__(512, 2) void k_fused_fb(const void* inputs, const void* masks,
                                                     const void* Wkv, const void* bkv,
                                                     const unsigned short* __restrict__ qws,
                                                     float* __restrict__ num,
                                                     float* __restrict__ den) {
  __shared__ unsigned short Abuf[128 * 64];
  __shared__ unsigned short Bbuf[256 * 64];
  __shared__ unsigned short kvbuf[128 * 128];
  __shared__ unsigned short vbuf[128 * 128];
  __shared__ unsigned short Pbuf[64 * 128];
  if (detect_fp32((const unsigned short*)inputs))
    fused_body_fb<float>((const float*)inputs, (const float*)masks, (const float*)Wkv,
                         (const float*)bkv, qws, num, den, Abuf, Bbuf, kvbuf, vbuf, Pbuf);
  else
    fused_body_fb<__hip_bfloat16>((const __hip_bfloat16*)inputs,
                                  (const __hip_bfloat16*)masks, (const __hip_bfloat16*)Wkv,
                                  (const __hip_bfloat16*)bkv, qws, num, den, Abuf, Bbuf,
                                  kvbuf, vbuf, Pbuf);
}

__global__ __launch_bounds__(256) void k_div_fb(const float* __restrict__ num,
                                                const float* __restrict__ den, void* out,
                                                const unsigned short* __restrict__ det) {
  int i = blockIdx.x * 256 + threadIdx.x;
  float v = num[i] / den[i >> 6];
  if (detect_fp32(det))
    ((float*)out)[i] = v;
  else
    ((__hip_bfloat16*)out)[i] = __float2bfloat16(v);
}

// ---------------------------------------------------------------------------
extern "C" void kernel_launch(void* const* d_in, const int* in_sizes, int n_in,
                              void* d_out, int out_size, void* d_ws, size_t ws_size,
                              hipStream_t stream) {
  // d_in: 0 inputs, 1 queries, 2 masks, 3 Wkv, 4 bkv, 5 Wq, 6 bq
  char* ws = (char*)d_ws;
  if (ws_size >= 119802880) {
    // NEW path. ws (bytes):
    //   [0]         conv region (bf16, 17,696,256 elems = 35,392,512 B)
    //   [35392512]  kv  bf16 [32768][1024]  (67,108,864 B)
    //   [102501376] qws bf16 [256][512]     (262,144 B)
    //   [102763520] num_part f32            (16,777,216 B)
    //   [119540736] den_part f32            (262,144 B)
    unsigned short* conv = (unsigned short*)ws;
    unsigned short* kv = (unsigned short*)(ws + 35392512);
    unsigned short* qws = (unsigned short*)(ws + 102501376);
    float* num_part = (float*)(ws + 102763520);
    float* den_part = (float*)(ws + 119540736);

    k_conv<<<2048, 256, 0, stream>>>(d_in[0], d_in[1], d_in[3], d_in[5], d_in[4], d_in[6],
                                     conv);
    k_gemm2<<<2056, 256, 0, stream>>>(conv, kv, qws);
    k_attn<<<dim3(32, 8), 512, 0, stream>>>(kv, qws, d_in[2], num_part, den_part,
                                            (const unsigned short*)d_in[0]);
    k_final<<<512, 256, 0, stream>>>(num_part, den_part, d_out,
                                     (const unsigned short*)d_in[0]);
  } else if (ws_size >= 802816) {
    // FALLBACK (R1 path). ws: [1024] den ; [16384] num ; [540672] qws
    float* den = (float*)(ws + 1024);
    float* num = (float*)(ws + 16384);
    unsigned short* qws = (unsigned short*)(ws + 540672);

    hipMemsetAsync(d_ws, 0, 540672, stream);
    dim3 gq(2, 4);
    k_qproj_fb<<<gq, 256, 0, stream>>>(d_in[1], d_in[5], d_in[6], qws,
                                       (const unsigned short*)d_in[0]);
    dim3 g2(32, 8, 4);
    k_fused_fb<<<g2, 512, 0, stream>>>(d_in[0], d_in[2], d_in[3], d_in[4], qws, num, den);
    k_div_fb<<<512, 256, 0, stream>>>(num, den, d_out, (const unsigned short*)d_in[0]);
  }
}